// Round 18
// baseline (313.294 us; speedup 1.0000x reference)
//
#include <hip/hip_runtime.h>
#include <hip/hip_bf16.h>
#include <stdint.h>

// Answer_Decoder: B=64, T=24, H=512, V=32000, E=256. All I/O float32.
// Attention is dead code (softmax over size-1 axis => ctx == cat(q,img)).
// Pipeline (4 dispatches):
//   0) prep: pack_w (bf16 Wpk) + zero flags/h-slot0   [off critical path]
//   1) g0_gemm: G0 = cat(emb[seq],q,img) @ W_ih0^T + b_ih0 + b_hh0 (gathered A)
//   2) lstm_wave (96 blocks): (t,layer) wavefront; W staged from bf16 Wpk
//      (round-16 version, measured 185us); h slab layout; h stores sc1;
//      A reads cached; per-block flags, wave-0-proxy poll + LDS broadcast.
//   3) fc_gemm (250 blocks): fcW panel in LDS; cached A; LDS-transposed
//      FULL-LINE f32x4 nt stores.

typedef short bf16x8 __attribute__((ext_vector_type(8)));
typedef float f32x4 __attribute__((ext_vector_type(4)));

#define NLSTM 96
#define NTILE_N 250          // 32000/128
#define HSLOT 32768          // elems per (layer,t) h slot: 32 slabs * 64 * 16

__device__ __forceinline__ unsigned short f2b(float f) {
    uint32_t u = __builtin_bit_cast(uint32_t, f);
    uint32_t r = u + 0x7FFFu + ((u >> 16) & 1u);
    return (unsigned short)(r >> 16);
}
__device__ __forceinline__ float fsig(float x) {
    float e = __expf(-x);
    return __builtin_amdgcn_rcpf(1.0f + e);
}
__device__ __forceinline__ float ftanh(float x) {
    float e = __expf(-2.0f * x);
    return (1.0f - e) * __builtin_amdgcn_rcpf(1.0f + e);
}
__device__ __forceinline__ bf16x8 cvt8(const float* p) {
    f32x4 v0 = *(const f32x4*)p;
    f32x4 v1 = *(const f32x4*)(p + 4);
    unsigned short o[8];
    #pragma unroll
    for (int x = 0; x < 4; ++x) { o[x] = f2b(v0[x]); o[4 + x] = f2b(v1[x]); }
    return *(bf16x8*)o;
}

// ---------------- prep: pack_w + zeroing ----------------
// blocks 0..6143: pack_w; blocks 6144..6151: zero flags + h slot0
__global__ __launch_bounds__(256) void prep(
    const float* __restrict__ Whh0,
    const float* __restrict__ Wih1, const float* __restrict__ Whh1,
    const float* __restrict__ Wih2, const float* __restrict__ Whh2,
    unsigned short* __restrict__ Wpk,
    unsigned int* __restrict__ flags,     // 2304 u32
    unsigned short* __restrict__ hst)
{
    int gid = blockIdx.x;
    int tid = threadIdx.x;
    if (gid < 6144) {
        int layer = gid / (32 * 64);
        int rem = gid % (32 * 64);
        int lbid = rem >> 6, r = rem & 63;
        int q = r >> 4, jj = r & 15;
        int grow = q * 512 + lbid * 16 + jj;
        int K = (layer == 0) ? 512 : 1024;
        size_t wbase = (layer == 0) ? 0
                     : (layer == 1) ? (size_t)32 * 64 * 512
                                    : (size_t)32 * 64 * 512 + (size_t)32 * 64 * 1024;
        unsigned short* dst = Wpk + wbase + ((size_t)lbid * 64 + r) * K;
        const float *s0, *s1 = nullptr;
        if (layer == 0)      { s0 = Whh0 + (size_t)grow * 512; }
        else if (layer == 1) { s0 = Wih1 + (size_t)grow * 512; s1 = Whh1 + (size_t)grow * 512; }
        else                 { s0 = Wih2 + (size_t)grow * 512; s1 = Whh2 + (size_t)grow * 512; }
        int half = tid >> 7, k4 = tid & 127;
        const float* src = (half == 0) ? s0 : s1;
        if (src) {
            f32x4 v = *(const f32x4*)&src[k4 * 4];
            unsigned short o[4];
            #pragma unroll
            for (int j = 0; j < 4; ++j) o[j] = f2b(v[j]);
            *(uint64_t*)&dst[half * 512 + k4 * 4] = *(uint64_t*)o;
        }
    } else {
        int z = (gid - 6144) * 256 + tid;          // 8 blocks * 256 = 2048
        for (int i = z; i < 2304; i += 2048) flags[i] = 0u;
        unsigned int* h32 = (unsigned int*)hst;
        for (int l = 0; l < 3; ++l) {
            unsigned int* base = h32 + (size_t)l * 25 * (HSLOT / 2);
            for (int i = z; i < HSLOT / 2; i += 2048) base[i] = 0u;
        }
    }
}

// ---------------- G0 GEMM: A gathered on the fly, W f32 in-staging --------
__global__ __launch_bounds__(256) void g0_gemm(
    const int* __restrict__ seq,
    const float* __restrict__ emb,
    const float* __restrict__ qf,
    const float* __restrict__ imf,
    const float* __restrict__ Wih0,       // [2048][1280] f32
    const float* __restrict__ bias0,
    const float* __restrict__ bias1,
    float* __restrict__ outf)             // G0 [1536][2048]
{
    __shared__ unsigned short lA[128 * 72];
    __shared__ unsigned short lB[128 * 72];
    const int m0 = (blockIdx.x % 12) * 128, n0 = (blockIdx.x / 12) * 128;
    const int tid = threadIdx.x;
    const int lane = tid & 63, wid = tid >> 6;
    const int wm = wid >> 1, wn = wid & 1;

    f32x4 acc[4][4] = {};

    for (int kt = 0; kt < 1280; kt += 64) {
        #pragma unroll
        for (int c = 0; c < 4; ++c) {
            int chunk = tid + c * 256;
            int row = chunk >> 3, kc = (chunk & 7) * 8;
            int k = kt + kc;
            int m = m0 + row, t = m >> 6, b = m & 63;
            const float* src;
            if (k < 256)      src = emb + (size_t)seq[b * 24 + t] * 256 + k;
            else if (k < 768) src = qf + b * 512 + (k - 256);
            else              src = imf + b * 512 + (k - 768);
            *(bf16x8*)&lA[row * 72 + kc] = cvt8(src);
            *(bf16x8*)&lB[row * 72 + kc] =
                cvt8(&Wih0[(size_t)(n0 + row) * 1280 + k]);
        }
        __syncthreads();
        #pragma unroll
        for (int ks = 0; ks < 64; ks += 32) {
            int kl = ks + ((lane >> 4) << 3);
            bf16x8 af[4], bfr[4];
            #pragma unroll
            for (int i = 0; i < 4; ++i)
                af[i] = *(const bf16x8*)&lA[(wm * 64 + i * 16 + (lane & 15)) * 72 + kl];
            #pragma unroll
            for (int j = 0; j < 4; ++j)
                bfr[j] = *(const bf16x8*)&lB[(wn * 64 + j * 16 + (lane & 15)) * 72 + kl];
            #pragma unroll
            for (int i = 0; i < 4; ++i)
                #pragma unroll
                for (int j = 0; j < 4; ++j)
                    acc[i][j] = __builtin_amdgcn_mfma_f32_16x16x32_bf16(
                        af[i], bfr[j], acc[i][j], 0, 0, 0);
        }
        __syncthreads();
    }

    #pragma unroll
    for (int i = 0; i < 4; ++i) {
        #pragma unroll
        for (int j = 0; j < 4; ++j) {
            int n = n0 + wn * 64 + j * 16 + (lane & 15);
            float bias = bias0[n] + bias1[n];
            #pragma unroll
            for (int r = 0; r < 4; ++r) {
                int m = m0 + wm * 64 + i * 16 + ((lane >> 4) << 2) + r;
                outf[(size_t)m * 2048 + n] = acc[i][j][r] + bias;
            }
        }
    }
}

// ---- lstm primitives: A reads NORMAL CACHED; h in slab layout ----
#define ISSUE_CHUNK(buf, kb0)                                                 \
    {                                                                         \
        _Pragma("unroll")                                                     \
        for (int u_ = 0; u_ < 8; ++u_) {                                      \
            int kg_ = (kb0) + u_ * 32 + lk;                                   \
            const unsigned short* hb_ = (kg_ < 512) ? A0 : A1;                \
            int kk_ = kg_ & 511;                                              \
            const unsigned short* ap_ =                                       \
                hb_ + ((kk_ >> 4) << 10) + brow16 + (kk_ & 15);               \
            asm volatile("global_load_dwordx4 %0, %1, off"                    \
                         : "=v"(buf[u_]) : "v"(ap_) : "memory");              \
        }                                                                     \
    }
#define MFMA_CHUNK(buf, kb0)                                                  \
    {                                                                         \
        _Pragma("unroll")                                                     \
        for (int u_ = 0; u_ < 8; ++u_) {                                      \
            int ksl_ = (kb0) + u_ * 32 + lk;                                  \
            _Pragma("unroll")                                                 \
            for (int q_ = 0; q_ < 4; ++q_) {                                  \
                int gx_ = ((ksl_ >> 3) ^ (lrow & 7)) << 3;                    \
                bf16x8 bq_ = *(const bf16x8*)&lb[(q_ * 16 + lrow) * K + gx_]; \
                acc[q_] = __builtin_amdgcn_mfma_f32_16x16x32_bf16(            \
                    buf[u_], bq_, acc[q_], 0, 0, 0);                          \
            }                                                                 \
        }                                                                     \
    }
#define VM_WAIT(n) { asm volatile("s_waitcnt vmcnt(" #n ")" ::: "memory");    \
                     __builtin_amdgcn_sched_barrier(0); }
#define POLL32(fbase)                                                         \
    {                                                                         \
        const unsigned int* fp_ = (fbase);                                    \
        int idx_ = lane & 31;                                                 \
        while (true) {                                                        \
            unsigned v_ = __hip_atomic_load((unsigned int*)&fp_[idx_],        \
                                            __ATOMIC_RELAXED,                 \
                                            __HIP_MEMORY_SCOPE_AGENT);       \
            if (__all(v_ != 0u)) break;                                       \
            __builtin_amdgcn_s_sleep(1);                                      \
        }                                                                     \
    }
#define LDS_SPIN(ptr)                                                         \
    {                                                                         \
        while (__hip_atomic_load((ptr), __ATOMIC_RELAXED,                     \
                                 __HIP_MEMORY_SCOPE_WORKGROUP) == 0u)         \
            __builtin_amdgcn_s_sleep(1);                                      \
    }

// ---------------- persistent wavefront LSTM (96 blocks) ----------------
// flags layout: [3][24][32 blocks] u32 (per-block, single-writer)
__global__ __launch_bounds__(256, 1) void lstm_wave(
    const unsigned short* __restrict__ Wpk,
    const float* __restrict__ G0,            // [24][64][2048]
    const float* __restrict__ bih1, const float* __restrict__ bhh1,
    const float* __restrict__ bih2, const float* __restrict__ bhh2,
    unsigned short* __restrict__ hst,        // [3][25][HSLOT] slab layout
    unsigned int* __restrict__ flags)        // [3][24][32]
{
    extern __shared__ char smem[];
    __shared__ unsigned int syncA[24];
    __shared__ unsigned int syncB[24];
    __shared__ unsigned int lcnt[24];
    unsigned short* lb = (unsigned short*)smem;   // [64][K], XOR-swizzled
    const int bid = blockIdx.x;
    const int tid = threadIdx.x;
    const int lane = tid & 63, w = tid >> 6;
    const int lrow = lane & 15, lk = (lane >> 4) * 8;
    const int layer = bid >> 5;
    const int lbid = bid & 31;
    const int j0 = lbid * 16;

    const int K = (layer == 0) ? 512 : 1024;
    const size_t wbase = (layer == 0) ? 0
                       : (layer == 1) ? (size_t)32 * 64 * 512
                                      : (size_t)32 * 64 * 512 + (size_t)32 * 64 * 1024;
    const unsigned short* Wblk = Wpk + wbase + (size_t)lbid * 64 * K;

    if (tid < 24) { syncA[tid] = 0u; syncB[tid] = 0u; lcnt[tid] = 0u; }
    {   // stage W once from bf16 Wpk, granule-XOR swizzle
        const int kshift = (layer == 0) ? 6 : 7;
        const int gm = (K >> 3) - 1;
        const int total = 64 << kshift;
        for (int idx = tid; idx < total; idx += 256) {
            int row = idx >> kshift, g = idx & gm;
            int gx = g ^ (row & 7);
            *(bf16x8*)&lb[row * K + gx * 8] =
                *(const bf16x8*)&Wblk[(size_t)row * K + g * 8];
        }
    }
    __syncthreads();   // the only block barrier

    unsigned short* hl = hst + (size_t)layer * 25 * HSLOT;
    const unsigned short* hlow =
        (layer > 0) ? hst + (size_t)(layer - 1) * 25 * HSLOT : nullptr;

    float pb[4] = {0.f, 0.f, 0.f, 0.f};
    if (layer == 1) {
        #pragma unroll
        for (int q = 0; q < 4; ++q)
            pb[q] = bih1[q * 512 + j0 + lrow] + bhh1[q * 512 + j0 + lrow];
    } else if (layer == 2) {
        #pragma unroll
        for (int q = 0; q < 4; ++q)
            pb[q] = bih2[q * 512 + j0 + lrow] + bhh2[q * 512 + j0 + lrow];
    }

    float creg[4] = {0.f, 0.f, 0.f, 0.f};
    const int brow16 = (w * 16 + lrow) << 4;

    for (int t = 0; t < 24; ++t) {
        // G0 prefetch (static, overlaps polls)
        float g0p[16];
        if (layer == 0) {
            const float* gp = G0 + (size_t)t * 64 * 2048;
            #pragma unroll
            for (int r = 0; r < 4; ++r) {
                int b = w * 16 + ((lane >> 4) << 2) + r;
                #pragma unroll
                for (int q = 0; q < 4; ++q)
                    g0p[r * 4 + q] = gp[(size_t)b * 2048 + q * 512 + j0 + lrow];
            }
        }

        const unsigned short* A0 = (layer == 0)
            ? hl + (size_t)t * HSLOT
            : hlow + (size_t)(t + 1) * HSLOT;
        const unsigned short* A1 = (layer == 0)
            ? A0
            : hl + (size_t)t * HSLOT;

        f32x4 acc[4] = {};
        bf16x8 bufA[8], bufB[8], bufC[8], bufD[8];

        if (layer == 0) {
            if (t > 0) {
                if (w == 0) {
                    POLL32(flags + (t - 1) * 32);
                    if (lane == 0)
                        __hip_atomic_store(&syncA[t], 1u, __ATOMIC_RELAXED,
                                           __HIP_MEMORY_SCOPE_WORKGROUP);
                } else {
                    LDS_SPIN(&syncA[t]);
                }
            }
            ISSUE_CHUNK(bufA, 0); ISSUE_CHUNK(bufB, 256);
            VM_WAIT(8); MFMA_CHUNK(bufA, 0);
            VM_WAIT(0); MFMA_CHUNK(bufB, 256);
        } else {
            if (t > 0) {
                if (w == 0) {
                    POLL32(flags + (layer * 24 + t - 1) * 32);
                    if (lane == 0)
                        __hip_atomic_store(&syncA[t], 1u, __ATOMIC_RELAXED,
                                           __HIP_MEMORY_SCOPE_WORKGROUP);
                } else {
                    LDS_SPIN(&syncA[t]);
                }
            }
            ISSUE_CHUNK(bufC, 512); ISSUE_CHUNK(bufD, 768);
            if (w == 0) {
                POLL32(flags + ((layer - 1) * 24 + t) * 32);
                if (lane == 0)
                    __hip_atomic_store(&syncB[t], 1u, __ATOMIC_RELAXED,
                                       __HIP_MEMORY_SCOPE_WORKGROUP);
            } else {
                LDS_SPIN(&syncB[t]);
            }
            ISSUE_CHUNK(bufA, 0); ISSUE_CHUNK(bufB, 256);
            VM_WAIT(24); MFMA_CHUNK(bufC, 512);
            VM_WAIT(16); MFMA_CHUNK(bufD, 768);
            VM_WAIT(8);  MFMA_CHUNK(bufA, 0);
            VM_WAIT(0);  MFMA_CHUNK(bufB, 256);
        }

        // epilogue; h stores: full-line slab writes, sc1 write-through
        unsigned short* hslot = hl + (size_t)(t + 1) * HSLOT + (lbid << 10);
        #pragma unroll
        for (int r = 0; r < 4; ++r) {
            int b = w * 16 + ((lane >> 4) << 2) + r;
            float g[4];
            #pragma unroll
            for (int q = 0; q < 4; ++q) {
                float p = (layer == 0) ? g0p[r * 4 + q] : pb[q];
                g[q] = acc[q][r] + p;
            }
            float ig = fsig(g[0]);
            float fg = fsig(g[1]);
            float gg = ftanh(g[2]);
            float og = fsig(g[3]);
            float cn = fg * creg[r] + ig * gg;
            creg[r] = cn;
            float h = og * ftanh(cn);
            unsigned int hb = (unsigned int)f2b(h);
            unsigned short* hp = hslot + (b << 4) + lrow;
            asm volatile("global_store_short %0, %1, off sc1"
                         :: "v"(hp), "v"(hb) : "memory");
        }
        asm volatile("s_waitcnt vmcnt(0)" ::: "memory");
        if (lane == 0) {
            unsigned old = __hip_atomic_fetch_add(&lcnt[t], 1u, __ATOMIC_RELAXED,
                                                  __HIP_MEMORY_SCOPE_WORKGROUP);
            if (old == 3u)
                __hip_atomic_store(&flags[(layer * 24 + t) * 32 + lbid], 1u,
                                   __ATOMIC_RELAXED, __HIP_MEMORY_SCOPE_AGENT);
        }
    }
}

// ---- fc: register-path A, NORMAL cached loads ----
#define FC_ISSUE_G(buf, mtv, ks0)                                             \
    {                                                                         \
        _Pragma("unroll")                                                     \
        for (int u_ = 0; u_ < 4; ++u_) {                                      \
            _Pragma("unroll")                                                 \
            for (int i_ = 0; i_ < 4; ++i_) {                                  \
                int rl_ = i_ * 16 + lrow;                                     \
                int k_ = (ks0) + u_ * 32 + lk;                                \
                const unsigned short* ap_ = h2                                \
                    + (size_t)(2 * (mtv) + wm + 1) * HSLOT                    \
                    + ((k_ >> 4) << 10) + (rl_ << 4) + (k_ & 15);             \
                asm volatile("global_load_dwordx4 %0, %1, off"                \
                             : "=v"(buf[u_ * 4 + i_]) : "v"(ap_) : "memory"); \
            }                                                                 \
        }                                                                     \
    }
#define FC_MFMA_G(buf, ks0)                                                   \
    {                                                                         \
        _Pragma("unroll")                                                     \
        for (int u_ = 0; u_ < 4; ++u_) {                                      \
            int ks_ = (ks0) + u_ * 32 + lk;                                   \
            _Pragma("unroll")                                                 \
            for (int jj_ = 0; jj_ < 4; ++jj_) {                               \
                int row_ = wn * 64 + jj_ * 16 + lrow;                         \
                int gx_ = ((ks_ >> 3) ^ (row_ & 7)) << 3;                     \
                bf16x8 bq_ = *(const bf16x8*)&lB[row_ * 512 + gx_];           \
                _Pragma("unroll")                                             \
                for (int i_ = 0; i_ < 4; ++i_)                                \
                    acc[i_][jj_] = __builtin_amdgcn_mfma_f32_16x16x32_bf16(   \
                        buf[u_ * 4 + i_], bq_, acc[i_][jj_], 0, 0, 0);        \
            }                                                                 \
        }                                                                     \
    }

// ---------------- fc GEMM (250 blocks, after wavefront) ----------------
__global__ __launch_bounds__(256, 1) void fc_gemm(
    const unsigned short* __restrict__ hst,
    const float* __restrict__ fcW,
    const float* __restrict__ fcb,
    float* __restrict__ out)
{
    extern __shared__ char smem[];
    unsigned short* lB = (unsigned short*)smem;       // [128][512] bf16 swz
    float* ltr = (float*)(smem + 131072);             // [64][128] f32 (32KB)
    const int tid = threadIdx.x;
    const int lane = tid & 63, w = tid >> 6;
    const int lrow = lane & 15, lk = (lane >> 4) * 8;
    const int wm = w >> 1, wn = w & 1;
    const unsigned short* h2 = hst + (size_t)2 * 25 * HSLOT;
    const int n0 = blockIdx.x * 128;

    // stage fcW panel once: f32 -> bf16, XOR swizzle
    for (int idx = tid; idx < 128 * 64; idx += 256) {
        int row = idx >> 6, g = idx & 63;
        *(bf16x8*)&lB[row * 512 + ((g ^ (row & 7)) << 3)] =
            cvt8(&fcW[(size_t)(n0 + row) * 512 + g * 8]);
    }
    const int cl = (tid & 31) * 4;
    f32x4 breg = *(const f32x4*)&fcb[n0 + cl];
    __syncthreads();

    bf16x8 gA[16], gB[16];
    FC_ISSUE_G(gA, 0, 0); FC_ISSUE_G(gB, 0, 128);

    for (int mt = 0; mt < 12; ++mt) {
        f32x4 acc[4][4] = {};
        VM_WAIT(16); FC_MFMA_G(gA, 0);
        FC_ISSUE_G(gA, mt, 256);
        VM_WAIT(16); FC_MFMA_G(gB, 128);
        FC_ISSUE_G(gB, mt, 384);
        VM_WAIT(16); FC_MFMA_G(gA, 256);
        VM_WAIT(0);  FC_MFMA_G(gB, 384);
        if (mt < 11) { FC_ISSUE_G(gA, mt + 1, 0); FC_ISSUE_G(gB, mt + 1, 128); }

        // epilogue: LDS transpose -> full-line f32x4 nt stores, 2 halves
        #pragma unroll
        for (int half = 0; half < 2; ++half) {
            if (wm == half) {
                #pragma unroll
                for (int i = 0; i < 4; ++i)
                    #pragma unroll
                    for (int jj = 0; jj < 4; ++jj)
                        #pragma unroll
                        for (int r = 0; r < 4; ++r)
                            ltr[(i * 16 + ((lane >> 4) << 2) + r) * 128
                                + wn * 64 + jj * 16 + lrow] = acc[i][jj][r];
            }
            __syncthreads();
            const int t_ = 2 * mt + half;
            #pragma unroll
            for (int rr = 0; rr < 8; ++rr) {
                int row = rr * 8 + (tid >> 5);        // = b
                f32x4 v = *(const f32x4*)&ltr[row * 128 + cl];
                v += breg;
                __builtin_nontemporal_store(v,
                    (f32x4*)&out[(size_t)(row * 24 + t_) * 32000 + n0 + cl]);
            }
            __syncthreads();
        }
    }
}

// ---------------- launch ----------------
extern "C" void kernel_launch(void* const* d_in, const int* in_sizes, int n_in,
                              void* d_out, int out_size, void* d_ws, size_t ws_size,
                              hipStream_t stream) {
    const float* qf  = (const float*)d_in[0];
    const float* imf = (const float*)d_in[1];
    const int*   seq = (const int*)d_in[2];
    const float* emb = (const float*)d_in[3];
    // d_in[4..6] dead code
    const float* fcW = (const float*)d_in[7];
    const float* fcb = (const float*)d_in[8];
    const float* Wih[3] = {(const float*)d_in[9],  (const float*)d_in[13], (const float*)d_in[17]};
    const float* Whh[3] = {(const float*)d_in[10], (const float*)d_in[14], (const float*)d_in[18]};
    const float* bih[3] = {(const float*)d_in[11], (const float*)d_in[15], (const float*)d_in[19]};
    const float* bhh[3] = {(const float*)d_in[12], (const float*)d_in[16], (const float*)d_in[20]};

    char* ws = (char*)d_ws;
    float*          G0    = (float*)(ws + 0);                   // 12,582,912
    unsigned short* hst   = (unsigned short*)(ws + 12582912);   // 4,915,200
    unsigned int*   flags = (unsigned int*)(ws + 17498112);     // 9,216
    unsigned short* Wpk   = (unsigned short*)(ws + 17507328);   // 10,485,760

    // 0) pack_w + zero flags/h-slot0 (off critical path)
    prep<<<6152, 256, 0, stream>>>(
        Whh[0], Wih[1], Whh[1], Wih[2], Whh[2], Wpk, flags, hst);

    // 1) G0 = cat(emb[seq], q, img) @ W_ih0^T + b_ih0 + b_hh0
    g0_gemm<<<192, 256, 0, stream>>>(
        seq, emb, qf, imf, Wih[0], bih[0], bhh[0], G0);

    // 2) wavefront: 96 blocks, 128 KiB dynamic LDS
    lstm_wave<<<NLSTM, 256, 131072, stream>>>(
        Wpk, G0, bih[1], bhh[1], bih[2], bhh[2], hst, flags);

    // 3) fc: 250 blocks, 160 KiB dynamic LDS
    fc_gemm<<<NTILE_N, 256, 163840, stream>>>(
        hst, fcW, fcb, (float*)d_out);
}

// Round 19
// 281.747 us; speedup vs baseline: 1.1120x; 1.1120x over previous
//
#include <hip/hip_runtime.h>
#include <hip/hip_bf16.h>
#include <stdint.h>

// Answer_Decoder: B=64, T=24, H=512, V=32000, E=256. All I/O float32.
// Attention is dead code (softmax over size-1 axis => ctx == cat(q,img)).
// Pipeline (4 dispatches)  [round-16 base + split-cell wavefront]:
//   0) prep: pack_w + build_x + zero(flags, h slot0)
//   1) gemm128: G0 = X @ W_ih0^T + b_ih0 + b_hh0
//   2) lstm_wave (96 blocks): (t,layer) wavefront; W persistent in LDS;
//      h slab layout; h stores sc1; A reads cached; wave-0-proxy poll +
//      LDS broadcast. SPLIT CELL: own-layer half-GEMM (loads + MFMA)
//      executes BEFORE the lower-layer poll (2 hops of slack), so the
//      critical inter-layer hop is only poll + 16 loads + 2 MFMA + epi.
//   3) fc_gemm (250 blocks): fcW panel in LDS; cached A; cross-tile
//      load/store decoupling (vmcnt(63) entry); nt out stores.

typedef short bf16x8 __attribute__((ext_vector_type(8)));
typedef float f32x4 __attribute__((ext_vector_type(4)));

#define NLSTM 96
#define NTILE_N 250          // 32000/128
#define HSLOT 32768          // elems per (layer,t) h slot: 32 slabs * 64 * 16

__device__ __forceinline__ unsigned short f2b(float f) {
    uint32_t u = __builtin_bit_cast(uint32_t, f);
    uint32_t r = u + 0x7FFFu + ((u >> 16) & 1u);
    return (unsigned short)(r >> 16);
}
__device__ __forceinline__ float fsig(float x) {
    float e = __expf(-x);
    return __builtin_amdgcn_rcpf(1.0f + e);
}
__device__ __forceinline__ float ftanh(float x) {
    float e = __expf(-2.0f * x);
    return (1.0f - e) * __builtin_amdgcn_rcpf(1.0f + e);
}

// ---------------- prep: pack_w + build_x + zeroing, one dispatch ----------
__global__ __launch_bounds__(256) void prep(
    const float* __restrict__ Whh0,
    const float* __restrict__ Wih1, const float* __restrict__ Whh1,
    const float* __restrict__ Wih2, const float* __restrict__ Whh2,
    unsigned short* __restrict__ Wpk,
    const float* __restrict__ qf,
    const float* __restrict__ imf,
    const int* __restrict__ seq,
    const float* __restrict__ emb,
    unsigned short* __restrict__ X,
    unsigned int* __restrict__ flags,     // 2304 u32
    unsigned short* __restrict__ hst)
{
    int gid = blockIdx.x;
    int tid = threadIdx.x;
    if (gid < 6144) {
        int layer = gid / (32 * 64);
        int rem = gid % (32 * 64);
        int lbid = rem >> 6, r = rem & 63;
        int q = r >> 4, jj = r & 15;
        int grow = q * 512 + lbid * 16 + jj;
        int K = (layer == 0) ? 512 : 1024;
        size_t wbase = (layer == 0) ? 0
                     : (layer == 1) ? (size_t)32 * 64 * 512
                                    : (size_t)32 * 64 * 512 + (size_t)32 * 64 * 1024;
        unsigned short* dst = Wpk + wbase + ((size_t)lbid * 64 + r) * K;
        const float *s0, *s1 = nullptr;
        if (layer == 0)      { s0 = Whh0 + (size_t)grow * 512; }
        else if (layer == 1) { s0 = Wih1 + (size_t)grow * 512; s1 = Whh1 + (size_t)grow * 512; }
        else                 { s0 = Wih2 + (size_t)grow * 512; s1 = Whh2 + (size_t)grow * 512; }
        int half = tid >> 7, k4 = tid & 127;       // 128 threads per half
        const float* src = (half == 0) ? s0 : s1;
        if (src) {
            f32x4 v = *(const f32x4*)&src[k4 * 4];
            unsigned short o[4];
            #pragma unroll
            for (int j = 0; j < 4; ++j) o[j] = f2b(v[j]);
            *(uint64_t*)&dst[half * 512 + k4 * 4] = *(uint64_t*)o;
        }
    } else if (gid < 7680) {
        int r = gid - 6144;
        int t = r >> 6, b = r & 63;
        int tok = seq[b * 24 + t];
        for (int e = tid; e < 1280; e += 256) {
            float v;
            if (e < 256)      v = emb[(size_t)tok * 256 + e];
            else if (e < 768) v = qf[b * 512 + (e - 256)];
            else              v = imf[b * 512 + (e - 768)];
            X[(size_t)r * 1280 + e] = f2b(v);
        }
    } else {
        int z = (gid - 7680) * 256 + tid;          // 8 blocks * 256 = 2048
        for (int i = z; i < 2304; i += 2048) flags[i] = 0u;
        unsigned int* h32 = (unsigned int*)hst;
        for (int l = 0; l < 3; ++l) {
            unsigned int* base = h32 + (size_t)l * 25 * (HSLOT / 2);
            for (int i = z; i < HSLOT / 2; i += 2048) base[i] = 0u;
        }
    }
}

// ---------------- 128x128 MFMA GEMM (G0): A bf16, W f32 (in-staging cvt) ----
__global__ __launch_bounds__(256) void gemm128(
    const unsigned short* __restrict__ A, int lda,
    const float* __restrict__ Wf, int ldb,
    int K,
    const float* __restrict__ bias0,
    const float* __restrict__ bias1,
    float* __restrict__ outf, int ldo, int mblocks, int xcdq)
{
    __shared__ unsigned short lA[128 * 72];
    __shared__ unsigned short lB[128 * 72];
    int lin = blockIdx.x;
    int wg = (lin & 7) * xcdq + (lin >> 3);
    const int m0 = (wg % mblocks) * 128, n0 = (wg / mblocks) * 128;
    const int tid = threadIdx.x;
    const int lane = tid & 63, wid = tid >> 6;
    const int wm = wid >> 1, wn = wid & 1;

    f32x4 acc[4][4] = {};

    for (int kt = 0; kt < K; kt += 64) {
        #pragma unroll
        for (int c = 0; c < 4; ++c) {
            int chunk = tid + c * 256;
            int row = chunk >> 3, kc = (chunk & 7) * 8;
            *(bf16x8*)&lA[row * 72 + kc] =
                *(const bf16x8*)&A[(size_t)(m0 + row) * lda + kt + kc];
            const float* bp = &Wf[(size_t)(n0 + row) * ldb + kt + kc];
            f32x4 v0 = *(const f32x4*)bp;
            f32x4 v1 = *(const f32x4*)(bp + 4);
            unsigned short o[8];
            #pragma unroll
            for (int x = 0; x < 4; ++x) { o[x] = f2b(v0[x]); o[4 + x] = f2b(v1[x]); }
            *(bf16x8*)&lB[row * 72 + kc] = *(bf16x8*)o;
        }
        __syncthreads();
        #pragma unroll
        for (int ks = 0; ks < 64; ks += 32) {
            int kl = ks + ((lane >> 4) << 3);
            bf16x8 af[4], bfr[4];
            #pragma unroll
            for (int i = 0; i < 4; ++i)
                af[i] = *(const bf16x8*)&lA[(wm * 64 + i * 16 + (lane & 15)) * 72 + kl];
            #pragma unroll
            for (int j = 0; j < 4; ++j)
                bfr[j] = *(const bf16x8*)&lB[(wn * 64 + j * 16 + (lane & 15)) * 72 + kl];
            #pragma unroll
            for (int i = 0; i < 4; ++i)
                #pragma unroll
                for (int j = 0; j < 4; ++j)
                    acc[i][j] = __builtin_amdgcn_mfma_f32_16x16x32_bf16(
                        af[i], bfr[j], acc[i][j], 0, 0, 0);
        }
        __syncthreads();
    }

    #pragma unroll
    for (int i = 0; i < 4; ++i) {
        #pragma unroll
        for (int j = 0; j < 4; ++j) {
            int n = n0 + wn * 64 + j * 16 + (lane & 15);
            float bias = bias0[n] + bias1[n];
            #pragma unroll
            for (int r = 0; r < 4; ++r) {
                int m = m0 + wm * 64 + i * 16 + ((lane >> 4) << 2) + r;
                outf[(size_t)m * ldo + n] = acc[i][j][r] + bias;
            }
        }
    }
}

// ---- lstm primitives: A reads NORMAL CACHED; h in slab layout ----
#define ISSUE_CHUNK(buf, kb0)                                                 \
    {                                                                         \
        _Pragma("unroll")                                                     \
        for (int u_ = 0; u_ < 8; ++u_) {                                      \
            int kg_ = (kb0) + u_ * 32 + lk;                                   \
            const unsigned short* hb_ = (kg_ < 512) ? A0 : A1;                \
            int kk_ = kg_ & 511;                                              \
            const unsigned short* ap_ =                                       \
                hb_ + ((kk_ >> 4) << 10) + brow16 + (kk_ & 15);               \
            asm volatile("global_load_dwordx4 %0, %1, off"                    \
                         : "=v"(buf[u_]) : "v"(ap_) : "memory");              \
        }                                                                     \
    }
#define MFMA_CHUNK(buf, kb0)                                                  \
    {                                                                         \
        _Pragma("unroll")                                                     \
        for (int u_ = 0; u_ < 8; ++u_) {                                      \
            int ksl_ = (kb0) + u_ * 32 + lk;                                  \
            _Pragma("unroll")                                                 \
            for (int q_ = 0; q_ < 4; ++q_) {                                  \
                int gx_ = ((ksl_ >> 3) ^ (lrow & 7)) << 3;                    \
                bf16x8 bq_ = *(const bf16x8*)&lb[(q_ * 16 + lrow) * K + gx_]; \
                acc[q_] = __builtin_amdgcn_mfma_f32_16x16x32_bf16(            \
                    buf[u_], bq_, acc[q_], 0, 0, 0);                          \
            }                                                                 \
        }                                                                     \
    }
#define VM_WAIT(n) { asm volatile("s_waitcnt vmcnt(" #n ")" ::: "memory");    \
                     __builtin_amdgcn_sched_barrier(0); }
#define POLL32(fbase)                                                         \
    {                                                                         \
        const unsigned int* fp_ = (fbase);                                    \
        int idx_ = lane & 31;                                                 \
        while (true) {                                                        \
            unsigned v_ = __hip_atomic_load((unsigned int*)&fp_[idx_],        \
                                            __ATOMIC_RELAXED,                 \
                                            __HIP_MEMORY_SCOPE_AGENT);       \
            if (__all(v_ != 0u)) break;                                       \
            __builtin_amdgcn_s_sleep(1);                                      \
        }                                                                     \
    }
#define LDS_SPIN(ptr)                                                         \
    {                                                                         \
        while (__hip_atomic_load((ptr), __ATOMIC_RELAXED,                     \
                                 __HIP_MEMORY_SCOPE_WORKGROUP) == 0u)         \
            __builtin_amdgcn_s_sleep(1);                                      \
    }

// ---------------- persistent wavefront LSTM (96 blocks) ----------------
// flags layout: [3][24][32 blocks] u32 (per-block, single-writer)
__global__ __launch_bounds__(256, 1) void lstm_wave(
    const unsigned short* __restrict__ Wpk,
    const float* __restrict__ G0,            // [24][64][2048]
    const float* __restrict__ bih1, const float* __restrict__ bhh1,
    const float* __restrict__ bih2, const float* __restrict__ bhh2,
    unsigned short* __restrict__ hst,        // [3][25][HSLOT] slab layout
    unsigned int* __restrict__ flags)        // [3][24][32]
{
    extern __shared__ char smem[];
    __shared__ unsigned int syncA[24];   // own-layer dep observed
    __shared__ unsigned int syncB[24];   // lower-layer dep observed
    __shared__ unsigned int lcnt[24];    // waves finished this t
    unsigned short* lb = (unsigned short*)smem;   // [64][K], XOR-swizzled
    const int bid = blockIdx.x;
    const int tid = threadIdx.x;
    const int lane = tid & 63, w = tid >> 6;
    const int lrow = lane & 15, lk = (lane >> 4) * 8;
    const int layer = bid >> 5;
    const int lbid = bid & 31;
    const int j0 = lbid * 16;

    const int K = (layer == 0) ? 512 : 1024;
    const size_t wbase = (layer == 0) ? 0
                       : (layer == 1) ? (size_t)32 * 64 * 512
                                      : (size_t)32 * 64 * 512 + (size_t)32 * 64 * 1024;
    const unsigned short* Wblk = Wpk + wbase + (size_t)lbid * 64 * K;

    if (tid < 24) { syncA[tid] = 0u; syncB[tid] = 0u; lcnt[tid] = 0u; }
    {   // stage W once, granule-XOR swizzle
        const int kshift = (layer == 0) ? 6 : 7;
        const int gm = (K >> 3) - 1;
        const int total = 64 << kshift;
        for (int idx = tid; idx < total; idx += 256) {
            int row = idx >> kshift, g = idx & gm;
            int gx = g ^ (row & 7);
            *(bf16x8*)&lb[row * K + gx * 8] =
                *(const bf16x8*)&Wblk[(size_t)row * K + g * 8];
        }
    }
    __syncthreads();   // the only block barrier

    unsigned short* hl = hst + (size_t)layer * 25 * HSLOT;
    const unsigned short* hlow =
        (layer > 0) ? hst + (size_t)(layer - 1) * 25 * HSLOT : nullptr;

    float pb[4] = {0.f, 0.f, 0.f, 0.f};
    if (layer == 1) {
        #pragma unroll
        for (int q = 0; q < 4; ++q)
            pb[q] = bih1[q * 512 + j0 + lrow] + bhh1[q * 512 + j0 + lrow];
    } else if (layer == 2) {
        #pragma unroll
        for (int q = 0; q < 4; ++q)
            pb[q] = bih2[q * 512 + j0 + lrow] + bhh2[q * 512 + j0 + lrow];
    }

    float creg[4] = {0.f, 0.f, 0.f, 0.f};
    const int brow16 = (w * 16 + lrow) << 4;

    for (int t = 0; t < 24; ++t) {
        // G0 prefetch (static, overlaps polls)
        float g0p[16];
        if (layer == 0) {
            const float* gp = G0 + (size_t)t * 64 * 2048;
            #pragma unroll
            for (int r = 0; r < 4; ++r) {
                int b = w * 16 + ((lane >> 4) << 2) + r;
                #pragma unroll
                for (int q = 0; q < 4; ++q)
                    g0p[r * 4 + q] = gp[(size_t)b * 2048 + q * 512 + j0 + lrow];
            }
        }

        const unsigned short* A0 = (layer == 0)
            ? hl + (size_t)t * HSLOT
            : hlow + (size_t)(t + 1) * HSLOT;
        const unsigned short* A1 = (layer == 0)
            ? A0
            : hl + (size_t)t * HSLOT;

        f32x4 acc[4] = {};
        bf16x8 bufA[8], bufB[8], bufC[8], bufD[8];

        if (layer == 0) {
            if (t > 0) {
                if (w == 0) {
                    POLL32(flags + (t - 1) * 32);
                    if (lane == 0)
                        __hip_atomic_store(&syncA[t], 1u, __ATOMIC_RELAXED,
                                           __HIP_MEMORY_SCOPE_WORKGROUP);
                } else {
                    LDS_SPIN(&syncA[t]);
                }
            }
            ISSUE_CHUNK(bufA, 0); ISSUE_CHUNK(bufB, 256);
            VM_WAIT(8); MFMA_CHUNK(bufA, 0);
            VM_WAIT(0); MFMA_CHUNK(bufB, 256);
        } else {
            // SPLIT CELL: own-layer half (h[l][t-1], 2 hops of slack) —
            // loads AND MFMAs execute before the lower-layer poll.
            if (t > 0) {
                if (w == 0) {
                    POLL32(flags + (layer * 24 + t - 1) * 32);
                    if (lane == 0)
                        __hip_atomic_store(&syncA[t], 1u, __ATOMIC_RELAXED,
                                           __HIP_MEMORY_SCOPE_WORKGROUP);
                } else {
                    LDS_SPIN(&syncA[t]);
                }
            }
            ISSUE_CHUNK(bufC, 512); ISSUE_CHUNK(bufD, 768);
            VM_WAIT(8); MFMA_CHUNK(bufC, 512);
            VM_WAIT(0); MFMA_CHUNK(bufD, 768);
            // critical inter-layer hop starts here
            if (w == 0) {
                POLL32(flags + ((layer - 1) * 24 + t) * 32);
                if (lane == 0)
                    __hip_atomic_store(&syncB[t], 1u, __ATOMIC_RELAXED,
                                       __HIP_MEMORY_SCOPE_WORKGROUP);
            } else {
                LDS_SPIN(&syncB[t]);
            }
            ISSUE_CHUNK(bufA, 0); ISSUE_CHUNK(bufB, 256);
            VM_WAIT(8); MFMA_CHUNK(bufA, 0);
            VM_WAIT(0); MFMA_CHUNK(bufB, 256);
        }

        // epilogue; h stores: full-line slab writes, sc1 write-through
        unsigned short* hslot = hl + (size_t)(t + 1) * HSLOT + (lbid << 10);
        #pragma unroll
        for (int r = 0; r < 4; ++r) {
            int b = w * 16 + ((lane >> 4) << 2) + r;
            float g[4];
            #pragma unroll
            for (int q = 0; q < 4; ++q) {
                float p = (layer == 0) ? g0p[r * 4 + q] : pb[q];
                g[q] = acc[q][r] + p;
            }
            float ig = fsig(g[0]);
            float fg = fsig(g[1]);
            float gg = ftanh(g[2]);
            float og = fsig(g[3]);
            float cn = fg * creg[r] + ig * gg;
            creg[r] = cn;
            float h = og * ftanh(cn);
            unsigned int hb = (unsigned int)f2b(h);
            unsigned short* hp = hslot + (b << 4) + lrow;
            asm volatile("global_store_short %0, %1, off sc1"
                         :: "v"(hp), "v"(hb) : "memory");
        }
        asm volatile("s_waitcnt vmcnt(0)" ::: "memory");
        if (lane == 0) {
            unsigned old = __hip_atomic_fetch_add(&lcnt[t], 1u, __ATOMIC_RELAXED,
                                                  __HIP_MEMORY_SCOPE_WORKGROUP);
            if (old == 3u)
                __hip_atomic_store(&flags[(layer * 24 + t) * 32 + lbid], 1u,
                                   __ATOMIC_RELAXED, __HIP_MEMORY_SCOPE_AGENT);
        }
    }
}

// ---- fc: register-path A, NORMAL cached loads (round-16 version) ----
#define FC_ISSUE_G(buf, mtv, ks0)                                             \
    {                                                                         \
        _Pragma("unroll")                                                     \
        for (int u_ = 0; u_ < 4; ++u_) {                                      \
            _Pragma("unroll")                                                 \
            for (int i_ = 0; i_ < 4; ++i_) {                                  \
                int rl_ = i_ * 16 + lrow;                                     \
                int k_ = (ks0) + u_ * 32 + lk;                                \
                const unsigned short* ap_ = h2                                \
                    + (size_t)(2 * (mtv) + wm + 1) * HSLOT                    \
                    + ((k_ >> 4) << 10) + (rl_ << 4) + (k_ & 15);             \
                asm volatile("global_load_dwordx4 %0, %1, off"                \
                             : "=v"(buf[u_ * 4 + i_]) : "v"(ap_) : "memory"); \
            }                                                                 \
        }                                                                     \
    }
#define FC_MFMA_G(buf, ks0)                                                   \
    {                                                                         \
        _Pragma("unroll")                                                     \
        for (int u_ = 0; u_ < 4; ++u_) {                                      \
            int ks_ = (ks0) + u_ * 32 + lk;                                   \
            _Pragma("unroll")                                                 \
            for (int jj_ = 0; jj_ < 4; ++jj_) {                               \
                int row_ = wn * 64 + jj_ * 16 + lrow;                         \
                int gx_ = ((ks_ >> 3) ^ (row_ & 7)) << 3;                     \
                bf16x8 bq_ = *(const bf16x8*)&lB[row_ * 512 + gx_];           \
                _Pragma("unroll")                                             \
                for (int i_ = 0; i_ < 4; ++i_)                                \
                    acc[i_][jj_] = __builtin_amdgcn_mfma_f32_16x16x32_bf16(   \
                        buf[u_ * 4 + i_], bq_, acc[i_][jj_], 0, 0, 0);        \
            }                                                                 \
        }                                                                     \
    }
#define FC_STORES                                                             \
    {                                                                         \
        _Pragma("unroll")                                                     \
        for (int i_ = 0; i_ < 4; ++i_) {                                      \
            _Pragma("unroll")                                                 \
            for (int jj_ = 0; jj_ < 4; ++jj_) {                               \
                int n_ = n0 + wn * 64 + jj_ * 16 + lrow;                      \
                float bias_ = fcb[n_];                                        \
                _Pragma("unroll")                                             \
                for (int r_ = 0; r_ < 4; ++r_) {                              \
                    int m_ = m0 + wm * 64 + i_ * 16 + ((lane >> 4) << 2) + r_;\
                    int b_ = m_ & 63, t_ = m_ >> 6;                           \
                    __builtin_nontemporal_store(                              \
                        acc[i_][jj_][r_] + bias_,                             \
                        &out[(size_t)(b_ * 24 + t_) * 32000 + n_]);           \
                }                                                             \
            }                                                                 \
        }                                                                     \
    }

// ---------------- fc GEMM (250 blocks, after wavefront) ----------------
__global__ __launch_bounds__(256, 1) void fc_gemm(
    const unsigned short* __restrict__ hst,
    const float* __restrict__ fcW,
    const float* __restrict__ fcb,
    float* __restrict__ out)
{
    extern __shared__ char smem[];
    unsigned short* lB = (unsigned short*)smem;    // [128][512] bf16 swizzled
    const int tid = threadIdx.x;
    const int lane = tid & 63, w = tid >> 6;
    const int lrow = lane & 15, lk = (lane >> 4) * 8;
    const int wm = w >> 1, wn = w & 1;
    const unsigned short* h2 = hst + (size_t)2 * 25 * HSLOT;
    const int n0 = blockIdx.x * 128;

    // stage fcW panel once: f32 -> bf16, XOR swizzle
    for (int idx = tid; idx < 128 * 64; idx += 256) {
        int row = idx >> 6, g = idx & 63;
        const float* bp = &fcW[(size_t)(n0 + row) * 512 + g * 8];
        f32x4 v0 = *(const f32x4*)bp;
        f32x4 v1 = *(const f32x4*)(bp + 4);
        unsigned short o[8];
        #pragma unroll
        for (int x = 0; x < 4; ++x) { o[x] = f2b(v0[x]); o[4 + x] = f2b(v1[x]); }
        *(bf16x8*)&lB[row * 512 + ((g ^ (row & 7)) << 3)] = *(bf16x8*)o;
    }
    __syncthreads();

    bf16x8 gA[16], gB[16];

    // ---- tile 0 (peeled: no stores in flight)
    {
        const int m0 = 0;
        f32x4 acc[4][4] = {};
        FC_ISSUE_G(gA, 0, 0); FC_ISSUE_G(gB, 0, 128);
        VM_WAIT(16); FC_MFMA_G(gA, 0);
        FC_ISSUE_G(gA, 0, 256);
        VM_WAIT(16); FC_MFMA_G(gB, 128);
        FC_ISSUE_G(gB, 0, 384);
        VM_WAIT(16); FC_MFMA_G(gA, 256);
        VM_WAIT(0);  FC_MFMA_G(gB, 384);
        FC_ISSUE_G(gA, 1, 0); FC_ISSUE_G(gB, 1, 128);
        FC_STORES;
    }

    for (int mt = 1; mt < 12; ++mt) {
        const int m0 = mt * 128;
        f32x4 acc[4][4] = {};
        // entry: 32 loads (oldest) + 64 stores outstanding = 96.
        // vmcnt(63) retires 33 oldest = all loads (+1 store).
        VM_WAIT(63);
        FC_MFMA_G(gA, 0);
        FC_ISSUE_G(gA, mt, 256);
        FC_MFMA_G(gB, 128);
        FC_ISSUE_G(gB, mt, 384);
        VM_WAIT(16);
        FC_MFMA_G(gA, 256);
        VM_WAIT(0);
        FC_MFMA_G(gB, 384);
        if (mt < 11) { FC_ISSUE_G(gA, mt + 1, 0); FC_ISSUE_G(gB, mt + 1, 128); }
        FC_STORES;
    }
}

// ---------------- launch ----------------
extern "C" void kernel_launch(void* const* d_in, const int* in_sizes, int n_in,
                              void* d_out, int out_size, void* d_ws, size_t ws_size,
                              hipStream_t stream) {
    const float* qf  = (const float*)d_in[0];
    const float* imf = (const float*)d_in[1];
    const int*   seq = (const int*)d_in[2];
    const float* emb = (const float*)d_in[3];
    // d_in[4..6] dead code
    const float* fcW = (const float*)d_in[7];
    const float* fcb = (const float*)d_in[8];
    const float* Wih[3] = {(const float*)d_in[9],  (const float*)d_in[13], (const float*)d_in[17]};
    const float* Whh[3] = {(const float*)d_in[10], (const float*)d_in[14], (const float*)d_in[18]};
    const float* bih[3] = {(const float*)d_in[11], (const float*)d_in[15], (const float*)d_in[19]};
    const float* bhh[3] = {(const float*)d_in[12], (const float*)d_in[16], (const float*)d_in[20]};

    char* ws = (char*)d_ws;
    unsigned short* X     = (unsigned short*)(ws + 0);          // 3,932,160
    float*          G0    = (float*)(ws + 3932160);             // 12,582,912
    unsigned short* hst   = (unsigned short*)(ws + 16515072);   // 4,915,200
    unsigned int*   flags = (unsigned int*)(ws + 21430272);     // 9,216
    unsigned short* Wpk   = (unsigned short*)(ws + 21467136);   // 10,485,760

    // 0) pack_w + build_x + zero(flags, h slot0)
    prep<<<7688, 256, 0, stream>>>(
        Whh[0], Wih[1], Whh[1], Wih[2], Whh[2], Wpk,
        qf, imf, seq, emb, X, flags, hst);

    // 1) G0 = X @ W_ih0^T + b_ih0 + b_hh0
    gemm128<<<192, 256, 0, stream>>>(
        X, 1280, Wih[0], 1280, 1280, bih[0], bhh[0], G0, 2048, 12, 192 / 8);

    // 2) wavefront: 96 blocks, 128 KiB dynamic LDS
    lstm_wave<<<NLSTM, 256, 131072, stream>>>(
        Wpk, G0, bih[1], bhh[1], bih[2], bhh[2], hst, flags);

    // 3) fc: 250 blocks, 128 KiB dynamic LDS
    fc_gemm<<<NTILE_N, 256, 131072, stream>>>(
        hst, fcW, fcb, (float*)d_out);
}

// Round 20
// 279.506 us; speedup vs baseline: 1.1209x; 1.0080x over previous
//
#include <hip/hip_runtime.h>
#include <hip/hip_bf16.h>
#include <stdint.h>

// Answer_Decoder: B=64, T=24, H=512, V=32000, E=256. All I/O float32.
// Attention is dead code (softmax over size-1 axis => ctx == cat(q,img)).
// Pipeline (4 dispatches)  [round-19 + fc store pairing]:
//   0) prep: pack_w + build_x + zero(flags, h slot0)
//   1) gemm128: G0 = X @ W_ih0^T + b_ih0 + b_hh0
//   2) lstm_wave (96 blocks): (t,layer) wavefront; W persistent in LDS;
//      h slab layout; h stores sc1; A reads cached; wave-0-proxy poll +
//      LDS broadcast; SPLIT CELL (own-layer half-GEMM before lower poll).
//   3) fc_gemm (250 blocks): fcW panel in LDS; cached A; cross-tile
//      load/store decoupling; nt stores ordered (i,r,jj) so each wave
//      emits 256B-contiguous runs per output row (full-line merging).

typedef short bf16x8 __attribute__((ext_vector_type(8)));
typedef float f32x4 __attribute__((ext_vector_type(4)));

#define NLSTM 96
#define NTILE_N 250          // 32000/128
#define HSLOT 32768          // elems per (layer,t) h slot: 32 slabs * 64 * 16

__device__ __forceinline__ unsigned short f2b(float f) {
    uint32_t u = __builtin_bit_cast(uint32_t, f);
    uint32_t r = u + 0x7FFFu + ((u >> 16) & 1u);
    return (unsigned short)(r >> 16);
}
__device__ __forceinline__ float fsig(float x) {
    float e = __expf(-x);
    return __builtin_amdgcn_rcpf(1.0f + e);
}
__device__ __forceinline__ float ftanh(float x) {
    float e = __expf(-2.0f * x);
    return (1.0f - e) * __builtin_amdgcn_rcpf(1.0f + e);
}

// ---------------- prep: pack_w + build_x + zeroing, one dispatch ----------
__global__ __launch_bounds__(256) void prep(
    const float* __restrict__ Whh0,
    const float* __restrict__ Wih1, const float* __restrict__ Whh1,
    const float* __restrict__ Wih2, const float* __restrict__ Whh2,
    unsigned short* __restrict__ Wpk,
    const float* __restrict__ qf,
    const float* __restrict__ imf,
    const int* __restrict__ seq,
    const float* __restrict__ emb,
    unsigned short* __restrict__ X,
    unsigned int* __restrict__ flags,     // 2304 u32
    unsigned short* __restrict__ hst)
{
    int gid = blockIdx.x;
    int tid = threadIdx.x;
    if (gid < 6144) {
        int layer = gid / (32 * 64);
        int rem = gid % (32 * 64);
        int lbid = rem >> 6, r = rem & 63;
        int q = r >> 4, jj = r & 15;
        int grow = q * 512 + lbid * 16 + jj;
        int K = (layer == 0) ? 512 : 1024;
        size_t wbase = (layer == 0) ? 0
                     : (layer == 1) ? (size_t)32 * 64 * 512
                                    : (size_t)32 * 64 * 512 + (size_t)32 * 64 * 1024;
        unsigned short* dst = Wpk + wbase + ((size_t)lbid * 64 + r) * K;
        const float *s0, *s1 = nullptr;
        if (layer == 0)      { s0 = Whh0 + (size_t)grow * 512; }
        else if (layer == 1) { s0 = Wih1 + (size_t)grow * 512; s1 = Whh1 + (size_t)grow * 512; }
        else                 { s0 = Wih2 + (size_t)grow * 512; s1 = Whh2 + (size_t)grow * 512; }
        int half = tid >> 7, k4 = tid & 127;       // 128 threads per half
        const float* src = (half == 0) ? s0 : s1;
        if (src) {
            f32x4 v = *(const f32x4*)&src[k4 * 4];
            unsigned short o[4];
            #pragma unroll
            for (int j = 0; j < 4; ++j) o[j] = f2b(v[j]);
            *(uint64_t*)&dst[half * 512 + k4 * 4] = *(uint64_t*)o;
        }
    } else if (gid < 7680) {
        int r = gid - 6144;
        int t = r >> 6, b = r & 63;
        int tok = seq[b * 24 + t];
        for (int e = tid; e < 1280; e += 256) {
            float v;
            if (e < 256)      v = emb[(size_t)tok * 256 + e];
            else if (e < 768) v = qf[b * 512 + (e - 256)];
            else              v = imf[b * 512 + (e - 768)];
            X[(size_t)r * 1280 + e] = f2b(v);
        }
    } else {
        int z = (gid - 7680) * 256 + tid;          // 8 blocks * 256 = 2048
        for (int i = z; i < 2304; i += 2048) flags[i] = 0u;
        unsigned int* h32 = (unsigned int*)hst;
        for (int l = 0; l < 3; ++l) {
            unsigned int* base = h32 + (size_t)l * 25 * (HSLOT / 2);
            for (int i = z; i < HSLOT / 2; i += 2048) base[i] = 0u;
        }
    }
}

// ---------------- 128x128 MFMA GEMM (G0): A bf16, W f32 (in-staging cvt) ----
__global__ __launch_bounds__(256) void gemm128(
    const unsigned short* __restrict__ A, int lda,
    const float* __restrict__ Wf, int ldb,
    int K,
    const float* __restrict__ bias0,
    const float* __restrict__ bias1,
    float* __restrict__ outf, int ldo, int mblocks, int xcdq)
{
    __shared__ unsigned short lA[128 * 72];
    __shared__ unsigned short lB[128 * 72];
    int lin = blockIdx.x;
    int wg = (lin & 7) * xcdq + (lin >> 3);
    const int m0 = (wg % mblocks) * 128, n0 = (wg / mblocks) * 128;
    const int tid = threadIdx.x;
    const int lane = tid & 63, wid = tid >> 6;
    const int wm = wid >> 1, wn = wid & 1;

    f32x4 acc[4][4] = {};

    for (int kt = 0; kt < K; kt += 64) {
        #pragma unroll
        for (int c = 0; c < 4; ++c) {
            int chunk = tid + c * 256;
            int row = chunk >> 3, kc = (chunk & 7) * 8;
            *(bf16x8*)&lA[row * 72 + kc] =
                *(const bf16x8*)&A[(size_t)(m0 + row) * lda + kt + kc];
            const float* bp = &Wf[(size_t)(n0 + row) * ldb + kt + kc];
            f32x4 v0 = *(const f32x4*)bp;
            f32x4 v1 = *(const f32x4*)(bp + 4);
            unsigned short o[8];
            #pragma unroll
            for (int x = 0; x < 4; ++x) { o[x] = f2b(v0[x]); o[4 + x] = f2b(v1[x]); }
            *(bf16x8*)&lB[row * 72 + kc] = *(bf16x8*)o;
        }
        __syncthreads();
        #pragma unroll
        for (int ks = 0; ks < 64; ks += 32) {
            int kl = ks + ((lane >> 4) << 3);
            bf16x8 af[4], bfr[4];
            #pragma unroll
            for (int i = 0; i < 4; ++i)
                af[i] = *(const bf16x8*)&lA[(wm * 64 + i * 16 + (lane & 15)) * 72 + kl];
            #pragma unroll
            for (int j = 0; j < 4; ++j)
                bfr[j] = *(const bf16x8*)&lB[(wn * 64 + j * 16 + (lane & 15)) * 72 + kl];
            #pragma unroll
            for (int i = 0; i < 4; ++i)
                #pragma unroll
                for (int j = 0; j < 4; ++j)
                    acc[i][j] = __builtin_amdgcn_mfma_f32_16x16x32_bf16(
                        af[i], bfr[j], acc[i][j], 0, 0, 0);
        }
        __syncthreads();
    }

    #pragma unroll
    for (int i = 0; i < 4; ++i) {
        #pragma unroll
        for (int j = 0; j < 4; ++j) {
            int n = n0 + wn * 64 + j * 16 + (lane & 15);
            float bias = bias0[n] + bias1[n];
            #pragma unroll
            for (int r = 0; r < 4; ++r) {
                int m = m0 + wm * 64 + i * 16 + ((lane >> 4) << 2) + r;
                outf[(size_t)m * ldo + n] = acc[i][j][r] + bias;
            }
        }
    }
}

// ---- lstm primitives: A reads NORMAL CACHED; h in slab layout ----
#define ISSUE_CHUNK(buf, kb0)                                                 \
    {                                                                         \
        _Pragma("unroll")                                                     \
        for (int u_ = 0; u_ < 8; ++u_) {                                      \
            int kg_ = (kb0) + u_ * 32 + lk;                                   \
            const unsigned short* hb_ = (kg_ < 512) ? A0 : A1;                \
            int kk_ = kg_ & 511;                                              \
            const unsigned short* ap_ =                                       \
                hb_ + ((kk_ >> 4) << 10) + brow16 + (kk_ & 15);               \
            asm volatile("global_load_dwordx4 %0, %1, off"                    \
                         : "=v"(buf[u_]) : "v"(ap_) : "memory");              \
        }                                                                     \
    }
#define MFMA_CHUNK(buf, kb0)                                                  \
    {                                                                         \
        _Pragma("unroll")                                                     \
        for (int u_ = 0; u_ < 8; ++u_) {                                      \
            int ksl_ = (kb0) + u_ * 32 + lk;                                  \
            _Pragma("unroll")                                                 \
            for (int q_ = 0; q_ < 4; ++q_) {                                  \
                int gx_ = ((ksl_ >> 3) ^ (lrow & 7)) << 3;                    \
                bf16x8 bq_ = *(const bf16x8*)&lb[(q_ * 16 + lrow) * K + gx_]; \
                acc[q_] = __builtin_amdgcn_mfma_f32_16x16x32_bf16(            \
                    buf[u_], bq_, acc[q_], 0, 0, 0);                          \
            }                                                                 \
        }                                                                     \
    }
#define VM_WAIT(n) { asm volatile("s_waitcnt vmcnt(" #n ")" ::: "memory");    \
                     __builtin_amdgcn_sched_barrier(0); }
#define POLL32(fbase)                                                         \
    {                                                                         \
        const unsigned int* fp_ = (fbase);                                    \
        int idx_ = lane & 31;                                                 \
        while (true) {                                                        \
            unsigned v_ = __hip_atomic_load((unsigned int*)&fp_[idx_],        \
                                            __ATOMIC_RELAXED,                 \
                                            __HIP_MEMORY_SCOPE_AGENT);       \
            if (__all(v_ != 0u)) break;                                       \
            __builtin_amdgcn_s_sleep(1);                                      \
        }                                                                     \
    }
#define LDS_SPIN(ptr)                                                         \
    {                                                                         \
        while (__hip_atomic_load((ptr), __ATOMIC_RELAXED,                     \
                                 __HIP_MEMORY_SCOPE_WORKGROUP) == 0u)         \
            __builtin_amdgcn_s_sleep(1);                                      \
    }

// ---------------- persistent wavefront LSTM (96 blocks) ----------------
// flags layout: [3][24][32 blocks] u32 (per-block, single-writer)
__global__ __launch_bounds__(256, 1) void lstm_wave(
    const unsigned short* __restrict__ Wpk,
    const float* __restrict__ G0,            // [24][64][2048]
    const float* __restrict__ bih1, const float* __restrict__ bhh1,
    const float* __restrict__ bih2, const float* __restrict__ bhh2,
    unsigned short* __restrict__ hst,        // [3][25][HSLOT] slab layout
    unsigned int* __restrict__ flags)        // [3][24][32]
{
    extern __shared__ char smem[];
    __shared__ unsigned int syncA[24];   // own-layer dep observed
    __shared__ unsigned int syncB[24];   // lower-layer dep observed
    __shared__ unsigned int lcnt[24];    // waves finished this t
    unsigned short* lb = (unsigned short*)smem;   // [64][K], XOR-swizzled
    const int bid = blockIdx.x;
    const int tid = threadIdx.x;
    const int lane = tid & 63, w = tid >> 6;
    const int lrow = lane & 15, lk = (lane >> 4) * 8;
    const int layer = bid >> 5;
    const int lbid = bid & 31;
    const int j0 = lbid * 16;

    const int K = (layer == 0) ? 512 : 1024;
    const size_t wbase = (layer == 0) ? 0
                       : (layer == 1) ? (size_t)32 * 64 * 512
                                      : (size_t)32 * 64 * 512 + (size_t)32 * 64 * 1024;
    const unsigned short* Wblk = Wpk + wbase + (size_t)lbid * 64 * K;

    if (tid < 24) { syncA[tid] = 0u; syncB[tid] = 0u; lcnt[tid] = 0u; }
    {   // stage W once, granule-XOR swizzle
        const int kshift = (layer == 0) ? 6 : 7;
        const int gm = (K >> 3) - 1;
        const int total = 64 << kshift;
        for (int idx = tid; idx < total; idx += 256) {
            int row = idx >> kshift, g = idx & gm;
            int gx = g ^ (row & 7);
            *(bf16x8*)&lb[row * K + gx * 8] =
                *(const bf16x8*)&Wblk[(size_t)row * K + g * 8];
        }
    }
    __syncthreads();   // the only block barrier

    unsigned short* hl = hst + (size_t)layer * 25 * HSLOT;
    const unsigned short* hlow =
        (layer > 0) ? hst + (size_t)(layer - 1) * 25 * HSLOT : nullptr;

    float pb[4] = {0.f, 0.f, 0.f, 0.f};
    if (layer == 1) {
        #pragma unroll
        for (int q = 0; q < 4; ++q)
            pb[q] = bih1[q * 512 + j0 + lrow] + bhh1[q * 512 + j0 + lrow];
    } else if (layer == 2) {
        #pragma unroll
        for (int q = 0; q < 4; ++q)
            pb[q] = bih2[q * 512 + j0 + lrow] + bhh2[q * 512 + j0 + lrow];
    }

    float creg[4] = {0.f, 0.f, 0.f, 0.f};
    const int brow16 = (w * 16 + lrow) << 4;

    for (int t = 0; t < 24; ++t) {
        // G0 prefetch (static, overlaps polls)
        float g0p[16];
        if (layer == 0) {
            const float* gp = G0 + (size_t)t * 64 * 2048;
            #pragma unroll
            for (int r = 0; r < 4; ++r) {
                int b = w * 16 + ((lane >> 4) << 2) + r;
                #pragma unroll
                for (int q = 0; q < 4; ++q)
                    g0p[r * 4 + q] = gp[(size_t)b * 2048 + q * 512 + j0 + lrow];
            }
        }

        const unsigned short* A0 = (layer == 0)
            ? hl + (size_t)t * HSLOT
            : hlow + (size_t)(t + 1) * HSLOT;
        const unsigned short* A1 = (layer == 0)
            ? A0
            : hl + (size_t)t * HSLOT;

        f32x4 acc[4] = {};
        bf16x8 bufA[8], bufB[8], bufC[8], bufD[8];

        if (layer == 0) {
            if (t > 0) {
                if (w == 0) {
                    POLL32(flags + (t - 1) * 32);
                    if (lane == 0)
                        __hip_atomic_store(&syncA[t], 1u, __ATOMIC_RELAXED,
                                           __HIP_MEMORY_SCOPE_WORKGROUP);
                } else {
                    LDS_SPIN(&syncA[t]);
                }
            }
            ISSUE_CHUNK(bufA, 0); ISSUE_CHUNK(bufB, 256);
            VM_WAIT(8); MFMA_CHUNK(bufA, 0);
            VM_WAIT(0); MFMA_CHUNK(bufB, 256);
        } else {
            // SPLIT CELL: own-layer half (h[l][t-1], 2 hops of slack) —
            // loads AND MFMAs execute before the lower-layer poll.
            if (t > 0) {
                if (w == 0) {
                    POLL32(flags + (layer * 24 + t - 1) * 32);
                    if (lane == 0)
                        __hip_atomic_store(&syncA[t], 1u, __ATOMIC_RELAXED,
                                           __HIP_MEMORY_SCOPE_WORKGROUP);
                } else {
                    LDS_SPIN(&syncA[t]);
                }
            }
            ISSUE_CHUNK(bufC, 512); ISSUE_CHUNK(bufD, 768);
            VM_WAIT(8); MFMA_CHUNK(bufC, 512);
            VM_WAIT(0); MFMA_CHUNK(bufD, 768);
            // critical inter-layer hop starts here
            if (w == 0) {
                POLL32(flags + ((layer - 1) * 24 + t) * 32);
                if (lane == 0)
                    __hip_atomic_store(&syncB[t], 1u, __ATOMIC_RELAXED,
                                       __HIP_MEMORY_SCOPE_WORKGROUP);
            } else {
                LDS_SPIN(&syncB[t]);
            }
            ISSUE_CHUNK(bufA, 0); ISSUE_CHUNK(bufB, 256);
            VM_WAIT(8); MFMA_CHUNK(bufA, 0);
            VM_WAIT(0); MFMA_CHUNK(bufB, 256);
        }

        // epilogue; h stores: full-line slab writes, sc1 write-through
        unsigned short* hslot = hl + (size_t)(t + 1) * HSLOT + (lbid << 10);
        #pragma unroll
        for (int r = 0; r < 4; ++r) {
            int b = w * 16 + ((lane >> 4) << 2) + r;
            float g[4];
            #pragma unroll
            for (int q = 0; q < 4; ++q) {
                float p = (layer == 0) ? g0p[r * 4 + q] : pb[q];
                g[q] = acc[q][r] + p;
            }
            float ig = fsig(g[0]);
            float fg = fsig(g[1]);
            float gg = ftanh(g[2]);
            float og = fsig(g[3]);
            float cn = fg * creg[r] + ig * gg;
            creg[r] = cn;
            float h = og * ftanh(cn);
            unsigned int hb = (unsigned int)f2b(h);
            unsigned short* hp = hslot + (b << 4) + lrow;
            asm volatile("global_store_short %0, %1, off sc1"
                         :: "v"(hp), "v"(hb) : "memory");
        }
        asm volatile("s_waitcnt vmcnt(0)" ::: "memory");
        if (lane == 0) {
            unsigned old = __hip_atomic_fetch_add(&lcnt[t], 1u, __ATOMIC_RELAXED,
                                                  __HIP_MEMORY_SCOPE_WORKGROUP);
            if (old == 3u)
                __hip_atomic_store(&flags[(layer * 24 + t) * 32 + lbid], 1u,
                                   __ATOMIC_RELAXED, __HIP_MEMORY_SCOPE_AGENT);
        }
    }
}

// ---- fc: register-path A, NORMAL cached loads ----
#define FC_ISSUE_G(buf, mtv, ks0)                                             \
    {                                                                         \
        _Pragma("unroll")                                                     \
        for (int u_ = 0; u_ < 4; ++u_) {                                      \
            _Pragma("unroll")                                                 \
            for (int i_ = 0; i_ < 4; ++i_) {                                  \
                int rl_ = i_ * 16 + lrow;                                     \
                int k_ = (ks0) + u_ * 32 + lk;                                \
                const unsigned short* ap_ = h2                                \
                    + (size_t)(2 * (mtv) + wm + 1) * HSLOT                    \
                    + ((k_ >> 4) << 10) + (rl_ << 4) + (k_ & 15);             \
                asm volatile("global_load_dwordx4 %0, %1, off"                \
                             : "=v"(buf[u_ * 4 + i_]) : "v"(ap_) : "memory"); \
            }                                                                 \
        }                                                                     \
    }
#define FC_MFMA_G(buf, ks0)                                                   \
    {                                                                         \
        _Pragma("unroll")                                                     \
        for (int u_ = 0; u_ < 4; ++u_) {                                      \
            int ks_ = (ks0) + u_ * 32 + lk;                                   \
            _Pragma("unroll")                                                 \
            for (int jj_ = 0; jj_ < 4; ++jj_) {                               \
                int row_ = wn * 64 + jj_ * 16 + lrow;                         \
                int gx_ = ((ks_ >> 3) ^ (row_ & 7)) << 3;                     \
                bf16x8 bq_ = *(const bf16x8*)&lB[row_ * 512 + gx_];           \
                _Pragma("unroll")                                             \
                for (int i_ = 0; i_ < 4; ++i_)                                \
                    acc[i_][jj_] = __builtin_amdgcn_mfma_f32_16x16x32_bf16(   \
                        buf[u_ * 4 + i_], bq_, acc[i_][jj_], 0, 0, 0);        \
            }                                                                 \
        }                                                                     \
    }
// store order (i, r, jj): per (i,r) the 4 jj-stores are 4 x 64B adjacent
// segments of ONE output row -> 256B contiguous per wave, full-line merge.
#define FC_STORES                                                             \
    {                                                                         \
        _Pragma("unroll")                                                     \
        for (int i_ = 0; i_ < 4; ++i_) {                                      \
            _Pragma("unroll")                                                 \
            for (int r_ = 0; r_ < 4; ++r_) {                                  \
                int m_ = m0 + wm * 64 + i_ * 16 + ((lane >> 4) << 2) + r_;    \
                int b_ = m_ & 63, t_ = m_ >> 6;                               \
                float* orow_ = &out[(size_t)(b_ * 24 + t_) * 32000];          \
                _Pragma("unroll")                                             \
                for (int jj_ = 0; jj_ < 4; ++jj_) {                           \
                    int n_ = n0 + wn * 64 + jj_ * 16 + lrow;                  \
                    __builtin_nontemporal_store(                              \
                        acc[i_][jj_][r_] + fcb[n_], &orow_[n_]);              \
                }                                                             \
            }                                                                 \
        }                                                                     \
    }

// ---------------- fc GEMM (250 blocks, after wavefront) ----------------
__global__ __launch_bounds__(256, 1) void fc_gemm(
    const unsigned short* __restrict__ hst,
    const float* __restrict__ fcW,
    const float* __restrict__ fcb,
    float* __restrict__ out)
{
    extern __shared__ char smem[];
    unsigned short* lB = (unsigned short*)smem;    // [128][512] bf16 swizzled
    const int tid = threadIdx.x;
    const int lane = tid & 63, w = tid >> 6;
    const int lrow = lane & 15, lk = (lane >> 4) * 8;
    const int wm = w >> 1, wn = w & 1;
    const unsigned short* h2 = hst + (size_t)2 * 25 * HSLOT;
    const int n0 = blockIdx.x * 128;

    // stage fcW panel once: f32 -> bf16, XOR swizzle
    for (int idx = tid; idx < 128 * 64; idx += 256) {
        int row = idx >> 6, g = idx & 63;
        const float* bp = &fcW[(size_t)(n0 + row) * 512 + g * 8];
        f32x4 v0 = *(const f32x4*)bp;
        f32x4 v1 = *(const f32x4*)(bp + 4);
        unsigned short o[8];
        #pragma unroll
        for (int x = 0; x < 4; ++x) { o[x] = f2b(v0[x]); o[4 + x] = f2b(v1[x]); }
        *(bf16x8*)&lB[row * 512 + ((g ^ (row & 7)) << 3)] = *(bf16x8*)o;
    }
    __syncthreads();

    bf16x8 gA[16], gB[16];

    // ---- tile 0 (peeled: no stores in flight)
    {
        const int m0 = 0;
        f32x4 acc[4][4] = {};
        FC_ISSUE_G(gA, 0, 0); FC_ISSUE_G(gB, 0, 128);
        VM_WAIT(16); FC_MFMA_G(gA, 0);
        FC_ISSUE_G(gA, 0, 256);
        VM_WAIT(16); FC_MFMA_G(gB, 128);
        FC_ISSUE_G(gB, 0, 384);
        VM_WAIT(16); FC_MFMA_G(gA, 256);
        VM_WAIT(0);  FC_MFMA_G(gB, 384);
        FC_ISSUE_G(gA, 1, 0); FC_ISSUE_G(gB, 1, 128);
        FC_STORES;
    }

    for (int mt = 1; mt < 12; ++mt) {
        const int m0 = mt * 128;
        f32x4 acc[4][4] = {};
        // entry: 32 loads (oldest) + 64 stores outstanding = 96.
        // vmcnt(63) retires 33 oldest = all loads (+1 store).
        VM_WAIT(63);
        FC_MFMA_G(gA, 0);
        FC_ISSUE_G(gA, mt, 256);
        FC_MFMA_G(gB, 128);
        FC_ISSUE_G(gB, mt, 384);
        VM_WAIT(16);
        FC_MFMA_G(gA, 256);
        VM_WAIT(0);
        FC_MFMA_G(gB, 384);
        if (mt < 11) { FC_ISSUE_G(gA, mt + 1, 0); FC_ISSUE_G(gB, mt + 1, 128); }
        FC_STORES;
    }
}

// ---------------- launch ----------------
extern "C" void kernel_launch(void* const* d_in, const int* in_sizes, int n_in,
                              void* d_out, int out_size, void* d_ws, size_t ws_size,
                              hipStream_t stream) {
    const float* qf  = (const float*)d_in[0];
    const float* imf = (const float*)d_in[1];
    const int*   seq = (const int*)d_in[2];
    const float* emb = (const float*)d_in[3];
    // d_in[4..6] dead code
    const float* fcW = (const float*)d_in[7];
    const float* fcb = (const float*)d_in[8];
    const float* Wih[3] = {(const float*)d_in[9],  (const float*)d_in[13], (const float*)d_in[17]};
    const float* Whh[3] = {(const float*)d_in[10], (const float*)d_in[14], (const float*)d_in[18]};
    const float* bih[3] = {(const float*)d_in[11], (const float*)d_in[15], (const float*)d_in[19]};
    const float* bhh[3] = {(const float*)d_in[12], (const float*)d_in[16], (const float*)d_in[20]};

    char* ws = (char*)d_ws;
    unsigned short* X     = (unsigned short*)(ws + 0);          // 3,932,160
    float*          G0    = (float*)(ws + 3932160);             // 12,582,912
    unsigned short* hst   = (unsigned short*)(ws + 16515072);   // 4,915,200
    unsigned int*   flags = (unsigned int*)(ws + 21430272);     // 9,216
    unsigned short* Wpk   = (unsigned short*)(ws + 21467136);   // 10,485,760

    // 0) pack_w + build_x + zero(flags, h slot0)
    prep<<<7688, 256, 0, stream>>>(
        Whh[0], Wih[1], Whh[1], Wih[2], Whh[2], Wpk,
        qf, imf, seq, emb, X, flags, hst);

    // 1) G0 = X @ W_ih0^T + b_ih0 + b_hh0
    gemm128<<<192, 256, 0, stream>>>(
        X, 1280, Wih[0], 1280, 1280, bih[0], bhh[0], G0, 2048, 12, 192 / 8);

    // 2) wavefront: 96 blocks, 128 KiB dynamic LDS
    lstm_wave<<<NLSTM, 256, 131072, stream>>>(
        Wpk, G0, bih[1], bhh[1], bih[2], bhh[2], hst, flags);

    // 3) fc: 250 blocks, 128 KiB dynamic LDS
    fc_gemm<<<NTILE_N, 256, 131072, stream>>>(
        hst, fcW, fcb, (float*)d_out);
}

// Round 21
// 266.197 us; speedup vs baseline: 1.1769x; 1.0500x over previous
//
#include <hip/hip_runtime.h>
#include <hip/hip_bf16.h>
#include <stdint.h>

// Answer_Decoder: B=64, T=24, H=512, V=32000, E=256. All I/O float32.
// Attention is dead code (softmax over size-1 axis => ctx == cat(q,img)).
// Pipeline (4 dispatches)  [round-20 + 512-thread fc]:
//   0) prep: pack_w + build_x + zero(flags, h slot0)
//   1) gemm128: G0 = X @ W_ih0^T + b_ih0 + b_hh0
//   2) lstm_wave (96 blocks): (t,layer) wavefront; W persistent in LDS;
//      h slab layout; h stores sc1; A reads cached; wave-0-proxy poll +
//      LDS broadcast; SPLIT CELL (own-layer half-GEMM before lower poll).
//   3) fc_gemm (250 blocks x 512 threads): fcW panel in LDS; 8 waves
//      (2/SIMD) so VM_WAIT stalls are covered by TLP; per-wave 32x64
//      sub-tile; cross-tile load/store decoupling; (i,r,jj) nt stores.

typedef short bf16x8 __attribute__((ext_vector_type(8)));
typedef float f32x4 __attribute__((ext_vector_type(4)));

#define NLSTM 96
#define NTILE_N 250          // 32000/128
#define HSLOT 32768          // elems per (layer,t) h slot: 32 slabs * 64 * 16

__device__ __forceinline__ unsigned short f2b(float f) {
    uint32_t u = __builtin_bit_cast(uint32_t, f);
    uint32_t r = u + 0x7FFFu + ((u >> 16) & 1u);
    return (unsigned short)(r >> 16);
}
__device__ __forceinline__ float fsig(float x) {
    float e = __expf(-x);
    return __builtin_amdgcn_rcpf(1.0f + e);
}
__device__ __forceinline__ float ftanh(float x) {
    float e = __expf(-2.0f * x);
    return (1.0f - e) * __builtin_amdgcn_rcpf(1.0f + e);
}

// ---------------- prep: pack_w + build_x + zeroing, one dispatch ----------
__global__ __launch_bounds__(256) void prep(
    const float* __restrict__ Whh0,
    const float* __restrict__ Wih1, const float* __restrict__ Whh1,
    const float* __restrict__ Wih2, const float* __restrict__ Whh2,
    unsigned short* __restrict__ Wpk,
    const float* __restrict__ qf,
    const float* __restrict__ imf,
    const int* __restrict__ seq,
    const float* __restrict__ emb,
    unsigned short* __restrict__ X,
    unsigned int* __restrict__ flags,     // 2304 u32
    unsigned short* __restrict__ hst)
{
    int gid = blockIdx.x;
    int tid = threadIdx.x;
    if (gid < 6144) {
        int layer = gid / (32 * 64);
        int rem = gid % (32 * 64);
        int lbid = rem >> 6, r = rem & 63;
        int q = r >> 4, jj = r & 15;
        int grow = q * 512 + lbid * 16 + jj;
        int K = (layer == 0) ? 512 : 1024;
        size_t wbase = (layer == 0) ? 0
                     : (layer == 1) ? (size_t)32 * 64 * 512
                                    : (size_t)32 * 64 * 512 + (size_t)32 * 64 * 1024;
        unsigned short* dst = Wpk + wbase + ((size_t)lbid * 64 + r) * K;
        const float *s0, *s1 = nullptr;
        if (layer == 0)      { s0 = Whh0 + (size_t)grow * 512; }
        else if (layer == 1) { s0 = Wih1 + (size_t)grow * 512; s1 = Whh1 + (size_t)grow * 512; }
        else                 { s0 = Wih2 + (size_t)grow * 512; s1 = Whh2 + (size_t)grow * 512; }
        int half = tid >> 7, k4 = tid & 127;       // 128 threads per half
        const float* src = (half == 0) ? s0 : s1;
        if (src) {
            f32x4 v = *(const f32x4*)&src[k4 * 4];
            unsigned short o[4];
            #pragma unroll
            for (int j = 0; j < 4; ++j) o[j] = f2b(v[j]);
            *(uint64_t*)&dst[half * 512 + k4 * 4] = *(uint64_t*)o;
        }
    } else if (gid < 7680) {
        int r = gid - 6144;
        int t = r >> 6, b = r & 63;
        int tok = seq[b * 24 + t];
        for (int e = tid; e < 1280; e += 256) {
            float v;
            if (e < 256)      v = emb[(size_t)tok * 256 + e];
            else if (e < 768) v = qf[b * 512 + (e - 256)];
            else              v = imf[b * 512 + (e - 768)];
            X[(size_t)r * 1280 + e] = f2b(v);
        }
    } else {
        int z = (gid - 7680) * 256 + tid;          // 8 blocks * 256 = 2048
        for (int i = z; i < 2304; i += 2048) flags[i] = 0u;
        unsigned int* h32 = (unsigned int*)hst;
        for (int l = 0; l < 3; ++l) {
            unsigned int* base = h32 + (size_t)l * 25 * (HSLOT / 2);
            for (int i = z; i < HSLOT / 2; i += 2048) base[i] = 0u;
        }
    }
}

// ---------------- 128x128 MFMA GEMM (G0): A bf16, W f32 (in-staging cvt) ----
__global__ __launch_bounds__(256) void gemm128(
    const unsigned short* __restrict__ A, int lda,
    const float* __restrict__ Wf, int ldb,
    int K,
    const float* __restrict__ bias0,
    const float* __restrict__ bias1,
    float* __restrict__ outf, int ldo, int mblocks, int xcdq)
{
    __shared__ unsigned short lA[128 * 72];
    __shared__ unsigned short lB[128 * 72];
    int lin = blockIdx.x;
    int wg = (lin & 7) * xcdq + (lin >> 3);
    const int m0 = (wg % mblocks) * 128, n0 = (wg / mblocks) * 128;
    const int tid = threadIdx.x;
    const int lane = tid & 63, wid = tid >> 6;
    const int wm = wid >> 1, wn = wid & 1;

    f32x4 acc[4][4] = {};

    for (int kt = 0; kt < K; kt += 64) {
        #pragma unroll
        for (int c = 0; c < 4; ++c) {
            int chunk = tid + c * 256;
            int row = chunk >> 3, kc = (chunk & 7) * 8;
            *(bf16x8*)&lA[row * 72 + kc] =
                *(const bf16x8*)&A[(size_t)(m0 + row) * lda + kt + kc];
            const float* bp = &Wf[(size_t)(n0 + row) * ldb + kt + kc];
            f32x4 v0 = *(const f32x4*)bp;
            f32x4 v1 = *(const f32x4*)(bp + 4);
            unsigned short o[8];
            #pragma unroll
            for (int x = 0; x < 4; ++x) { o[x] = f2b(v0[x]); o[4 + x] = f2b(v1[x]); }
            *(bf16x8*)&lB[row * 72 + kc] = *(bf16x8*)o;
        }
        __syncthreads();
        #pragma unroll
        for (int ks = 0; ks < 64; ks += 32) {
            int kl = ks + ((lane >> 4) << 3);
            bf16x8 af[4], bfr[4];
            #pragma unroll
            for (int i = 0; i < 4; ++i)
                af[i] = *(const bf16x8*)&lA[(wm * 64 + i * 16 + (lane & 15)) * 72 + kl];
            #pragma unroll
            for (int j = 0; j < 4; ++j)
                bfr[j] = *(const bf16x8*)&lB[(wn * 64 + j * 16 + (lane & 15)) * 72 + kl];
            #pragma unroll
            for (int i = 0; i < 4; ++i)
                #pragma unroll
                for (int j = 0; j < 4; ++j)
                    acc[i][j] = __builtin_amdgcn_mfma_f32_16x16x32_bf16(
                        af[i], bfr[j], acc[i][j], 0, 0, 0);
        }
        __syncthreads();
    }

    #pragma unroll
    for (int i = 0; i < 4; ++i) {
        #pragma unroll
        for (int j = 0; j < 4; ++j) {
            int n = n0 + wn * 64 + j * 16 + (lane & 15);
            float bias = bias0[n] + bias1[n];
            #pragma unroll
            for (int r = 0; r < 4; ++r) {
                int m = m0 + wm * 64 + i * 16 + ((lane >> 4) << 2) + r;
                outf[(size_t)m * ldo + n] = acc[i][j][r] + bias;
            }
        }
    }
}

// ---- lstm primitives: A reads NORMAL CACHED; h in slab layout ----
#define ISSUE_CHUNK(buf, kb0)                                                 \
    {                                                                         \
        _Pragma("unroll")                                                     \
        for (int u_ = 0; u_ < 8; ++u_) {                                      \
            int kg_ = (kb0) + u_ * 32 + lk;                                   \
            const unsigned short* hb_ = (kg_ < 512) ? A0 : A1;                \
            int kk_ = kg_ & 511;                                              \
            const unsigned short* ap_ =                                       \
                hb_ + ((kk_ >> 4) << 10) + brow16 + (kk_ & 15);               \
            asm volatile("global_load_dwordx4 %0, %1, off"                    \
                         : "=v"(buf[u_]) : "v"(ap_) : "memory");              \
        }                                                                     \
    }
#define MFMA_CHUNK(buf, kb0)                                                  \
    {                                                                         \
        _Pragma("unroll")                                                     \
        for (int u_ = 0; u_ < 8; ++u_) {                                      \
            int ksl_ = (kb0) + u_ * 32 + lk;                                  \
            _Pragma("unroll")                                                 \
            for (int q_ = 0; q_ < 4; ++q_) {                                  \
                int gx_ = ((ksl_ >> 3) ^ (lrow & 7)) << 3;                    \
                bf16x8 bq_ = *(const bf16x8*)&lb[(q_ * 16 + lrow) * K + gx_]; \
                acc[q_] = __builtin_amdgcn_mfma_f32_16x16x32_bf16(            \
                    buf[u_], bq_, acc[q_], 0, 0, 0);                          \
            }                                                                 \
        }                                                                     \
    }
#define VM_WAIT(n) { asm volatile("s_waitcnt vmcnt(" #n ")" ::: "memory");    \
                     __builtin_amdgcn_sched_barrier(0); }
#define POLL32(fbase)                                                         \
    {                                                                         \
        const unsigned int* fp_ = (fbase);                                    \
        int idx_ = lane & 31;                                                 \
        while (true) {                                                        \
            unsigned v_ = __hip_atomic_load((unsigned int*)&fp_[idx_],        \
                                            __ATOMIC_RELAXED,                 \
                                            __HIP_MEMORY_SCOPE_AGENT);       \
            if (__all(v_ != 0u)) break;                                       \
            __builtin_amdgcn_s_sleep(1);                                      \
        }                                                                     \
    }
#define LDS_SPIN(ptr)                                                         \
    {                                                                         \
        while (__hip_atomic_load((ptr), __ATOMIC_RELAXED,                     \
                                 __HIP_MEMORY_SCOPE_WORKGROUP) == 0u)         \
            __builtin_amdgcn_s_sleep(1);                                      \
    }

// ---------------- persistent wavefront LSTM (96 blocks) ----------------
// flags layout: [3][24][32 blocks] u32 (per-block, single-writer)
__global__ __launch_bounds__(256, 1) void lstm_wave(
    const unsigned short* __restrict__ Wpk,
    const float* __restrict__ G0,            // [24][64][2048]
    const float* __restrict__ bih1, const float* __restrict__ bhh1,
    const float* __restrict__ bih2, const float* __restrict__ bhh2,
    unsigned short* __restrict__ hst,        // [3][25][HSLOT] slab layout
    unsigned int* __restrict__ flags)        // [3][24][32]
{
    extern __shared__ char smem[];
    __shared__ unsigned int syncA[24];   // own-layer dep observed
    __shared__ unsigned int syncB[24];   // lower-layer dep observed
    __shared__ unsigned int lcnt[24];    // waves finished this t
    unsigned short* lb = (unsigned short*)smem;   // [64][K], XOR-swizzled
    const int bid = blockIdx.x;
    const int tid = threadIdx.x;
    const int lane = tid & 63, w = tid >> 6;
    const int lrow = lane & 15, lk = (lane >> 4) * 8;
    const int layer = bid >> 5;
    const int lbid = bid & 31;
    const int j0 = lbid * 16;

    const int K = (layer == 0) ? 512 : 1024;
    const size_t wbase = (layer == 0) ? 0
                       : (layer == 1) ? (size_t)32 * 64 * 512
                                      : (size_t)32 * 64 * 512 + (size_t)32 * 64 * 1024;
    const unsigned short* Wblk = Wpk + wbase + (size_t)lbid * 64 * K;

    if (tid < 24) { syncA[tid] = 0u; syncB[tid] = 0u; lcnt[tid] = 0u; }
    {   // stage W once, granule-XOR swizzle
        const int kshift = (layer == 0) ? 6 : 7;
        const int gm = (K >> 3) - 1;
        const int total = 64 << kshift;
        for (int idx = tid; idx < total; idx += 256) {
            int row = idx >> kshift, g = idx & gm;
            int gx = g ^ (row & 7);
            *(bf16x8*)&lb[row * K + gx * 8] =
                *(const bf16x8*)&Wblk[(size_t)row * K + g * 8];
        }
    }
    __syncthreads();   // the only block barrier

    unsigned short* hl = hst + (size_t)layer * 25 * HSLOT;
    const unsigned short* hlow =
        (layer > 0) ? hst + (size_t)(layer - 1) * 25 * HSLOT : nullptr;

    float pb[4] = {0.f, 0.f, 0.f, 0.f};
    if (layer == 1) {
        #pragma unroll
        for (int q = 0; q < 4; ++q)
            pb[q] = bih1[q * 512 + j0 + lrow] + bhh1[q * 512 + j0 + lrow];
    } else if (layer == 2) {
        #pragma unroll
        for (int q = 0; q < 4; ++q)
            pb[q] = bih2[q * 512 + j0 + lrow] + bhh2[q * 512 + j0 + lrow];
    }

    float creg[4] = {0.f, 0.f, 0.f, 0.f};
    const int brow16 = (w * 16 + lrow) << 4;

    for (int t = 0; t < 24; ++t) {
        // G0 prefetch (static, overlaps polls)
        float g0p[16];
        if (layer == 0) {
            const float* gp = G0 + (size_t)t * 64 * 2048;
            #pragma unroll
            for (int r = 0; r < 4; ++r) {
                int b = w * 16 + ((lane >> 4) << 2) + r;
                #pragma unroll
                for (int q = 0; q < 4; ++q)
                    g0p[r * 4 + q] = gp[(size_t)b * 2048 + q * 512 + j0 + lrow];
            }
        }

        const unsigned short* A0 = (layer == 0)
            ? hl + (size_t)t * HSLOT
            : hlow + (size_t)(t + 1) * HSLOT;
        const unsigned short* A1 = (layer == 0)
            ? A0
            : hl + (size_t)t * HSLOT;

        f32x4 acc[4] = {};
        bf16x8 bufA[8], bufB[8], bufC[8], bufD[8];

        if (layer == 0) {
            if (t > 0) {
                if (w == 0) {
                    POLL32(flags + (t - 1) * 32);
                    if (lane == 0)
                        __hip_atomic_store(&syncA[t], 1u, __ATOMIC_RELAXED,
                                           __HIP_MEMORY_SCOPE_WORKGROUP);
                } else {
                    LDS_SPIN(&syncA[t]);
                }
            }
            ISSUE_CHUNK(bufA, 0); ISSUE_CHUNK(bufB, 256);
            VM_WAIT(8); MFMA_CHUNK(bufA, 0);
            VM_WAIT(0); MFMA_CHUNK(bufB, 256);
        } else {
            // SPLIT CELL: own-layer half (h[l][t-1], 2 hops of slack) —
            // loads AND MFMAs execute before the lower-layer poll.
            if (t > 0) {
                if (w == 0) {
                    POLL32(flags + (layer * 24 + t - 1) * 32);
                    if (lane == 0)
                        __hip_atomic_store(&syncA[t], 1u, __ATOMIC_RELAXED,
                                           __HIP_MEMORY_SCOPE_WORKGROUP);
                } else {
                    LDS_SPIN(&syncA[t]);
                }
            }
            ISSUE_CHUNK(bufC, 512); ISSUE_CHUNK(bufD, 768);
            VM_WAIT(8); MFMA_CHUNK(bufC, 512);
            VM_WAIT(0); MFMA_CHUNK(bufD, 768);
            // critical inter-layer hop starts here
            if (w == 0) {
                POLL32(flags + ((layer - 1) * 24 + t) * 32);
                if (lane == 0)
                    __hip_atomic_store(&syncB[t], 1u, __ATOMIC_RELAXED,
                                       __HIP_MEMORY_SCOPE_WORKGROUP);
            } else {
                LDS_SPIN(&syncB[t]);
            }
            ISSUE_CHUNK(bufA, 0); ISSUE_CHUNK(bufB, 256);
            VM_WAIT(8); MFMA_CHUNK(bufA, 0);
            VM_WAIT(0); MFMA_CHUNK(bufB, 256);
        }

        // epilogue; h stores: full-line slab writes, sc1 write-through
        unsigned short* hslot = hl + (size_t)(t + 1) * HSLOT + (lbid << 10);
        #pragma unroll
        for (int r = 0; r < 4; ++r) {
            int b = w * 16 + ((lane >> 4) << 2) + r;
            float g[4];
            #pragma unroll
            for (int q = 0; q < 4; ++q) {
                float p = (layer == 0) ? g0p[r * 4 + q] : pb[q];
                g[q] = acc[q][r] + p;
            }
            float ig = fsig(g[0]);
            float fg = fsig(g[1]);
            float gg = ftanh(g[2]);
            float og = fsig(g[3]);
            float cn = fg * creg[r] + ig * gg;
            creg[r] = cn;
            float h = og * ftanh(cn);
            unsigned int hb = (unsigned int)f2b(h);
            unsigned short* hp = hslot + (b << 4) + lrow;
            asm volatile("global_store_short %0, %1, off sc1"
                         :: "v"(hp), "v"(hb) : "memory");
        }
        asm volatile("s_waitcnt vmcnt(0)" ::: "memory");
        if (lane == 0) {
            unsigned old = __hip_atomic_fetch_add(&lcnt[t], 1u, __ATOMIC_RELAXED,
                                                  __HIP_MEMORY_SCOPE_WORKGROUP);
            if (old == 3u)
                __hip_atomic_store(&flags[(layer * 24 + t) * 32 + lbid], 1u,
                                   __ATOMIC_RELAXED, __HIP_MEMORY_SCOPE_AGENT);
        }
    }
}

// ---- fc (512 threads): per-wave 32x64 sub-tile, cached A loads ----
// wave w: wm=w>>1 (0..3) -> t-half = wm>>1, b-half = (wm&1)*32 ; wn = w&1.
#define FC_ISSUE_G(buf, mtv, ks0)                                             \
    {                                                                         \
        _Pragma("unroll")                                                     \
        for (int u_ = 0; u_ < 4; ++u_) {                                      \
            _Pragma("unroll")                                                 \
            for (int i_ = 0; i_ < 2; ++i_) {                                  \
                int b_ = brow + i_ * 16 + lrow;                               \
                int k_ = (ks0) + u_ * 32 + lk;                                \
                const unsigned short* ap_ = h2                                \
                    + (size_t)(2 * (mtv) + thalf + 1) * HSLOT                 \
                    + ((k_ >> 4) << 10) + (b_ << 4) + (k_ & 15);              \
                asm volatile("global_load_dwordx4 %0, %1, off"                \
                             : "=v"(buf[u_ * 2 + i_]) : "v"(ap_) : "memory"); \
            }                                                                 \
        }                                                                     \
    }
#define FC_MFMA_G(buf, ks0)                                                   \
    {                                                                         \
        _Pragma("unroll")                                                     \
        for (int u_ = 0; u_ < 4; ++u_) {                                      \
            int ks_ = (ks0) + u_ * 32 + lk;                                   \
            _Pragma("unroll")                                                 \
            for (int jj_ = 0; jj_ < 4; ++jj_) {                               \
                int row_ = wn * 64 + jj_ * 16 + lrow;                         \
                int gx_ = ((ks_ >> 3) ^ (row_ & 7)) << 3;                     \
                bf16x8 bq_ = *(const bf16x8*)&lB[row_ * 512 + gx_];           \
                _Pragma("unroll")                                             \
                for (int i_ = 0; i_ < 2; ++i_)                                \
                    acc[i_][jj_] = __builtin_amdgcn_mfma_f32_16x16x32_bf16(   \
                        buf[u_ * 2 + i_], bq_, acc[i_][jj_], 0, 0, 0);        \
            }                                                                 \
        }                                                                     \
    }
// store order (i, r, jj): 256B-contiguous runs per output row
#define FC_STORES                                                             \
    {                                                                         \
        int t_ = 2 * mt + thalf;                                              \
        _Pragma("unroll")                                                     \
        for (int i_ = 0; i_ < 2; ++i_) {                                      \
            _Pragma("unroll")                                                 \
            for (int r_ = 0; r_ < 4; ++r_) {                                  \
                int b_ = brow + i_ * 16 + ((lane >> 4) << 2) + r_;            \
                float* orow_ = &out[(size_t)(b_ * 24 + t_) * 32000];          \
                _Pragma("unroll")                                             \
                for (int jj_ = 0; jj_ < 4; ++jj_) {                           \
                    int n_ = n0 + wn * 64 + jj_ * 16 + lrow;                  \
                    __builtin_nontemporal_store(                              \
                        acc[i_][jj_][r_] + fcb[n_], &orow_[n_]);              \
                }                                                             \
            }                                                                 \
        }                                                                     \
    }

// ---------------- fc GEMM (250 blocks x 512 threads) ----------------
__global__ __launch_bounds__(512, 1) void fc_gemm(
    const unsigned short* __restrict__ hst,
    const float* __restrict__ fcW,
    const float* __restrict__ fcb,
    float* __restrict__ out)
{
    extern __shared__ char smem[];
    unsigned short* lB = (unsigned short*)smem;    // [128][512] bf16 swizzled
    const int tid = threadIdx.x;
    const int lane = tid & 63, w = tid >> 6;       // w in 0..7
    const int lrow = lane & 15, lk = (lane >> 4) * 8;
    const int wm = w >> 1, wn = w & 1;
    const int thalf = wm >> 1;                     // t within tile pair
    const int brow = (wm & 1) * 32;                // batch-row half
    const unsigned short* h2 = hst + (size_t)2 * 25 * HSLOT;
    const int n0 = blockIdx.x * 128;

    // stage fcW panel once: f32 -> bf16, XOR swizzle
    for (int idx = tid; idx < 128 * 64; idx += 512) {
        int row = idx >> 6, g = idx & 63;
        const float* bp = &fcW[(size_t)(n0 + row) * 512 + g * 8];
        f32x4 v0 = *(const f32x4*)bp;
        f32x4 v1 = *(const f32x4*)(bp + 4);
        unsigned short o[8];
        #pragma unroll
        for (int x = 0; x < 4; ++x) { o[x] = f2b(v0[x]); o[4 + x] = f2b(v1[x]); }
        *(bf16x8*)&lB[row * 512 + ((g ^ (row & 7)) << 3)] = *(bf16x8*)o;
    }
    __syncthreads();

    bf16x8 gA[8], gB[8];

    // ---- tile 0 (peeled: no stores in flight)
    {
        const int mt = 0;
        f32x4 acc[2][4] = {};
        FC_ISSUE_G(gA, 0, 0); FC_ISSUE_G(gB, 0, 128);
        VM_WAIT(8); FC_MFMA_G(gA, 0);
        FC_ISSUE_G(gA, 0, 256);
        VM_WAIT(8); FC_MFMA_G(gB, 128);
        FC_ISSUE_G(gB, 0, 384);
        VM_WAIT(8); FC_MFMA_G(gA, 256);
        VM_WAIT(0); FC_MFMA_G(gB, 384);
        FC_ISSUE_G(gA, 1, 0); FC_ISSUE_G(gB, 1, 128);   // prefetch next
        FC_STORES;                                      // 32 stores
    }

    for (int mt = 1; mt < 12; ++mt) {
        f32x4 acc[2][4] = {};
        // entry: 16 loads (oldest) + 32 stores = 48 outstanding.
        // vmcnt(32) retires exactly the 16 loads.
        VM_WAIT(32);
        FC_MFMA_G(gA, 0);
        FC_ISSUE_G(gA, mt, 256);
        FC_MFMA_G(gB, 128);
        FC_ISSUE_G(gB, mt, 384);
        VM_WAIT(8);    // stores drained during the 2 MFMA groups
        FC_MFMA_G(gA, 256);
        VM_WAIT(0);
        FC_MFMA_G(gB, 384);
        if (mt < 11) { FC_ISSUE_G(gA, mt + 1, 0); FC_ISSUE_G(gB, mt + 1, 128); }
        FC_STORES;
    }
}

// ---------------- launch ----------------
extern "C" void kernel_launch(void* const* d_in, const int* in_sizes, int n_in,
                              void* d_out, int out_size, void* d_ws, size_t ws_size,
                              hipStream_t stream) {
    const float* qf  = (const float*)d_in[0];
    const float* imf = (const float*)d_in[1];
    const int*   seq = (const int*)d_in[2];
    const float* emb = (const float*)d_in[3];
    // d_in[4..6] dead code
    const float* fcW = (const float*)d_in[7];
    const float* fcb = (const float*)d_in[8];
    const float* Wih[3] = {(const float*)d_in[9],  (const float*)d_in[13], (const float*)d_in[17]};
    const float* Whh[3] = {(const float*)d_in[10], (const float*)d_in[14], (const float*)d_in[18]};
    const float* bih[3] = {(const float*)d_in[11], (const float*)d_in[15], (const float*)d_in[19]};
    const float* bhh[3] = {(const float*)d_in[12], (const float*)d_in[16], (const float*)d_in[20]};

    char* ws = (char*)d_ws;
    unsigned short* X     = (unsigned short*)(ws + 0);          // 3,932,160
    float*          G0    = (float*)(ws + 3932160);             // 12,582,912
    unsigned short* hst   = (unsigned short*)(ws + 16515072);   // 4,915,200
    unsigned int*   flags = (unsigned int*)(ws + 21430272);     // 9,216
    unsigned short* Wpk   = (unsigned short*)(ws + 21467136);   // 10,485,760

    // 0) pack_w + build_x + zero(flags, h slot0)
    prep<<<7688, 256, 0, stream>>>(
        Whh[0], Wih[1], Whh[1], Wih[2], Whh[2], Wpk,
        qf, imf, seq, emb, X, flags, hst);

    // 1) G0 = X @ W_ih0^T + b_ih0 + b_hh0
    gemm128<<<192, 256, 0, stream>>>(
        X, 1280, Wih[0], 1280, 1280, bih[0], bhh[0], G0, 2048, 12, 192 / 8);

    // 2) wavefront: 96 blocks, 128 KiB dynamic LDS
    lstm_wave<<<NLSTM, 256, 131072, stream>>>(
        Wpk, G0, bih[1], bhh[1], bih[2], bhh[2], hst, flags);

    // 3) fc: 250 blocks x 512 threads, 128 KiB dynamic LDS
    fc_gemm<<<NTILE_N, 512, 131072, stream>>>(
        hst, fcW, fcb, (float*)d_out);
}

// Round 22
// 264.783 us; speedup vs baseline: 1.1832x; 1.0053x over previous
//
#include <hip/hip_runtime.h>
#include <hip/hip_bf16.h>
#include <stdint.h>

// Answer_Decoder: B=64, T=24, H=512, V=32000, E=256. All I/O float32.
// Attention is dead code (softmax over size-1 axis => ctx == cat(q,img)).
// Pipeline (3 dispatches)  [round-21 + prologue consolidation]:
//   0) prep: build_x + zero(flags, h slot0)            (1544 blocks)
//   1) g0pack: blocks 0..191 = G0 GEMM; 192..6335 = pack_w (concurrent,
//      pack_w hides under G0; saves one launch gap)
//   2) lstm_wave (96 blocks): (t,layer) wavefront; W persistent in LDS;
//      h slab layout; h stores sc1; A reads cached; wave-0-proxy poll +
//      LDS broadcast; SPLIT CELL (own-layer half-GEMM before lower poll).
//   3) fc_gemm (250 blocks x 512 threads): fcW panel in LDS; 8 waves
//      (2/SIMD) for TLP over VM_WAIT stalls; cross-tile decoupling.

typedef short bf16x8 __attribute__((ext_vector_type(8)));
typedef float f32x4 __attribute__((ext_vector_type(4)));

#define NLSTM 96
#define NTILE_N 250          // 32000/128
#define HSLOT 32768          // elems per (layer,t) h slot: 32 slabs * 64 * 16

__device__ __forceinline__ unsigned short f2b(float f) {
    uint32_t u = __builtin_bit_cast(uint32_t, f);
    uint32_t r = u + 0x7FFFu + ((u >> 16) & 1u);
    return (unsigned short)(r >> 16);
}
__device__ __forceinline__ float fsig(float x) {
    float e = __expf(-x);
    return __builtin_amdgcn_rcpf(1.0f + e);
}
__device__ __forceinline__ float ftanh(float x) {
    float e = __expf(-2.0f * x);
    return (1.0f - e) * __builtin_amdgcn_rcpf(1.0f + e);
}

// ---------------- prep: build_x + zeroing ----------------
__global__ __launch_bounds__(256) void prep(
    const float* __restrict__ qf,
    const float* __restrict__ imf,
    const int* __restrict__ seq,
    const float* __restrict__ emb,
    unsigned short* __restrict__ X,
    unsigned int* __restrict__ flags,     // 2304 u32
    unsigned short* __restrict__ hst)
{
    int gid = blockIdx.x;
    int tid = threadIdx.x;
    if (gid < 1536) {
        int r = gid;
        int t = r >> 6, b = r & 63;
        int tok = seq[b * 24 + t];
        for (int e = tid; e < 1280; e += 256) {
            float v;
            if (e < 256)      v = emb[(size_t)tok * 256 + e];
            else if (e < 768) v = qf[b * 512 + (e - 256)];
            else              v = imf[b * 512 + (e - 768)];
            X[(size_t)r * 1280 + e] = f2b(v);
        }
    } else {
        int z = (gid - 1536) * 256 + tid;          // 8 blocks * 256 = 2048
        for (int i = z; i < 2304; i += 2048) flags[i] = 0u;
        unsigned int* h32 = (unsigned int*)hst;
        for (int l = 0; l < 3; ++l) {
            unsigned int* base = h32 + (size_t)l * 25 * (HSLOT / 2);
            for (int i = z; i < HSLOT / 2; i += 2048) base[i] = 0u;
        }
    }
}

// ---------------- g0pack: G0 GEMM (blocks 0..191) + pack_w (192..6335) ----
__global__ __launch_bounds__(256) void g0pack(
    const unsigned short* __restrict__ A,      // X [1536][1280] bf16
    const float* __restrict__ Wih0,            // [2048][1280] f32
    const float* __restrict__ bias0,
    const float* __restrict__ bias1,
    float* __restrict__ outf,                  // G0 [1536][2048]
    const float* __restrict__ Whh0,
    const float* __restrict__ Wih1, const float* __restrict__ Whh1,
    const float* __restrict__ Wih2, const float* __restrict__ Whh2,
    unsigned short* __restrict__ Wpk)
{
    const int tid = threadIdx.x;
    if (blockIdx.x >= 192) {
        // ---- pack_w path
        int gid = blockIdx.x - 192;            // 0..6143
        int layer = gid / (32 * 64);
        int rem = gid % (32 * 64);
        int lbid = rem >> 6, r = rem & 63;
        int q = r >> 4, jj = r & 15;
        int grow = q * 512 + lbid * 16 + jj;
        int K = (layer == 0) ? 512 : 1024;
        size_t wbase = (layer == 0) ? 0
                     : (layer == 1) ? (size_t)32 * 64 * 512
                                    : (size_t)32 * 64 * 512 + (size_t)32 * 64 * 1024;
        unsigned short* dst = Wpk + wbase + ((size_t)lbid * 64 + r) * K;
        const float *s0, *s1 = nullptr;
        if (layer == 0)      { s0 = Whh0 + (size_t)grow * 512; }
        else if (layer == 1) { s0 = Wih1 + (size_t)grow * 512; s1 = Whh1 + (size_t)grow * 512; }
        else                 { s0 = Wih2 + (size_t)grow * 512; s1 = Whh2 + (size_t)grow * 512; }
        int half = tid >> 7, k4 = tid & 127;
        const float* src = (half == 0) ? s0 : s1;
        if (src) {
            f32x4 v = *(const f32x4*)&src[k4 * 4];
            unsigned short o[4];
            #pragma unroll
            for (int j = 0; j < 4; ++j) o[j] = f2b(v[j]);
            *(uint64_t*)&dst[half * 512 + k4 * 4] = *(uint64_t*)o;
        }
        return;
    }
    // ---- G0 GEMM path: M=1536, N=2048, K=1280, tile 128x128
    __shared__ unsigned short lA[128 * 72];
    __shared__ unsigned short lB[128 * 72];
    const int m0 = (blockIdx.x % 12) * 128, n0 = (blockIdx.x / 12) * 128;
    const int lane = tid & 63, wid = tid >> 6;
    const int wm = wid >> 1, wn = wid & 1;

    f32x4 acc[4][4] = {};

    for (int kt = 0; kt < 1280; kt += 64) {
        #pragma unroll
        for (int c = 0; c < 4; ++c) {
            int chunk = tid + c * 256;
            int row = chunk >> 3, kc = (chunk & 7) * 8;
            *(bf16x8*)&lA[row * 72 + kc] =
                *(const bf16x8*)&A[(size_t)(m0 + row) * 1280 + kt + kc];
            const float* bp = &Wih0[(size_t)(n0 + row) * 1280 + kt + kc];
            f32x4 v0 = *(const f32x4*)bp;
            f32x4 v1 = *(const f32x4*)(bp + 4);
            unsigned short o[8];
            #pragma unroll
            for (int x = 0; x < 4; ++x) { o[x] = f2b(v0[x]); o[4 + x] = f2b(v1[x]); }
            *(bf16x8*)&lB[row * 72 + kc] = *(bf16x8*)o;
        }
        __syncthreads();
        #pragma unroll
        for (int ks = 0; ks < 64; ks += 32) {
            int kl = ks + ((lane >> 4) << 3);
            bf16x8 af[4], bfr[4];
            #pragma unroll
            for (int i = 0; i < 4; ++i)
                af[i] = *(const bf16x8*)&lA[(wm * 64 + i * 16 + (lane & 15)) * 72 + kl];
            #pragma unroll
            for (int j = 0; j < 4; ++j)
                bfr[j] = *(const bf16x8*)&lB[(wn * 64 + j * 16 + (lane & 15)) * 72 + kl];
            #pragma unroll
            for (int i = 0; i < 4; ++i)
                #pragma unroll
                for (int j = 0; j < 4; ++j)
                    acc[i][j] = __builtin_amdgcn_mfma_f32_16x16x32_bf16(
                        af[i], bfr[j], acc[i][j], 0, 0, 0);
        }
        __syncthreads();
    }

    #pragma unroll
    for (int i = 0; i < 4; ++i) {
        #pragma unroll
        for (int j = 0; j < 4; ++j) {
            int n = n0 + wn * 64 + j * 16 + (lane & 15);
            float bias = bias0[n] + bias1[n];
            #pragma unroll
            for (int r = 0; r < 4; ++r) {
                int m = m0 + wm * 64 + i * 16 + ((lane >> 4) << 2) + r;
                outf[(size_t)m * 2048 + n] = acc[i][j][r] + bias;
            }
        }
    }
}

// ---- lstm primitives: A reads NORMAL CACHED; h in slab layout ----
#define ISSUE_CHUNK(buf, kb0)                                                 \
    {                                                                         \
        _Pragma("unroll")                                                     \
        for (int u_ = 0; u_ < 8; ++u_) {                                      \
            int kg_ = (kb0) + u_ * 32 + lk;                                   \
            const unsigned short* hb_ = (kg_ < 512) ? A0 : A1;                \
            int kk_ = kg_ & 511;                                              \
            const unsigned short* ap_ =                                       \
                hb_ + ((kk_ >> 4) << 10) + brow16 + (kk_ & 15);               \
            asm volatile("global_load_dwordx4 %0, %1, off"                    \
                         : "=v"(buf[u_]) : "v"(ap_) : "memory");              \
        }                                                                     \
    }
#define MFMA_CHUNK(buf, kb0)                                                  \
    {                                                                         \
        _Pragma("unroll")                                                     \
        for (int u_ = 0; u_ < 8; ++u_) {                                      \
            int ksl_ = (kb0) + u_ * 32 + lk;                                  \
            _Pragma("unroll")                                                 \
            for (int q_ = 0; q_ < 4; ++q_) {                                  \
                int gx_ = ((ksl_ >> 3) ^ (lrow & 7)) << 3;                    \
                bf16x8 bq_ = *(const bf16x8*)&lb[(q_ * 16 + lrow) * K + gx_]; \
                acc[q_] = __builtin_amdgcn_mfma_f32_16x16x32_bf16(            \
                    buf[u_], bq_, acc[q_], 0, 0, 0);                          \
            }                                                                 \
        }                                                                     \
    }
#define VM_WAIT(n) { asm volatile("s_waitcnt vmcnt(" #n ")" ::: "memory");    \
                     __builtin_amdgcn_sched_barrier(0); }
#define POLL32(fbase)                                                         \
    {                                                                         \
        const unsigned int* fp_ = (fbase);                                    \
        int idx_ = lane & 31;                                                 \
        while (true) {                                                        \
            unsigned v_ = __hip_atomic_load((unsigned int*)&fp_[idx_],        \
                                            __ATOMIC_RELAXED,                 \
                                            __HIP_MEMORY_SCOPE_AGENT);       \
            if (__all(v_ != 0u)) break;                                       \
            __builtin_amdgcn_s_sleep(1);                                      \
        }                                                                     \
    }
#define LDS_SPIN(ptr)                                                         \
    {                                                                         \
        while (__hip_atomic_load((ptr), __ATOMIC_RELAXED,                     \
                                 __HIP_MEMORY_SCOPE_WORKGROUP) == 0u)         \
            __builtin_amdgcn_s_sleep(1);                                      \
    }

// ---------------- persistent wavefront LSTM (96 blocks) ----------------
// flags layout: [3][24][32 blocks] u32 (per-block, single-writer)
__global__ __launch_bounds__(256, 1) void lstm_wave(
    const unsigned short* __restrict__ Wpk,
    const float* __restrict__ G0,            // [24][64][2048]
    const float* __restrict__ bih1, const float* __restrict__ bhh1,
    const float* __restrict__ bih2, const float* __restrict__ bhh2,
    unsigned short* __restrict__ hst,        // [3][25][HSLOT] slab layout
    unsigned int* __restrict__ flags)        // [3][24][32]
{
    extern __shared__ char smem[];
    __shared__ unsigned int syncA[24];   // own-layer dep observed
    __shared__ unsigned int syncB[24];   // lower-layer dep observed
    __shared__ unsigned int lcnt[24];    // waves finished this t
    unsigned short* lb = (unsigned short*)smem;   // [64][K], XOR-swizzled
    const int bid = blockIdx.x;
    const int tid = threadIdx.x;
    const int lane = tid & 63, w = tid >> 6;
    const int lrow = lane & 15, lk = (lane >> 4) * 8;
    const int layer = bid >> 5;
    const int lbid = bid & 31;
    const int j0 = lbid * 16;

    const int K = (layer == 0) ? 512 : 1024;
    const size_t wbase = (layer == 0) ? 0
                       : (layer == 1) ? (size_t)32 * 64 * 512
                                      : (size_t)32 * 64 * 512 + (size_t)32 * 64 * 1024;
    const unsigned short* Wblk = Wpk + wbase + (size_t)lbid * 64 * K;

    if (tid < 24) { syncA[tid] = 0u; syncB[tid] = 0u; lcnt[tid] = 0u; }
    {   // stage W once, granule-XOR swizzle
        const int kshift = (layer == 0) ? 6 : 7;
        const int gm = (K >> 3) - 1;
        const int total = 64 << kshift;
        for (int idx = tid; idx < total; idx += 256) {
            int row = idx >> kshift, g = idx & gm;
            int gx = g ^ (row & 7);
            *(bf16x8*)&lb[row * K + gx * 8] =
                *(const bf16x8*)&Wblk[(size_t)row * K + g * 8];
        }
    }
    __syncthreads();   // the only block barrier

    unsigned short* hl = hst + (size_t)layer * 25 * HSLOT;
    const unsigned short* hlow =
        (layer > 0) ? hst + (size_t)(layer - 1) * 25 * HSLOT : nullptr;

    float pb[4] = {0.f, 0.f, 0.f, 0.f};
    if (layer == 1) {
        #pragma unroll
        for (int q = 0; q < 4; ++q)
            pb[q] = bih1[q * 512 + j0 + lrow] + bhh1[q * 512 + j0 + lrow];
    } else if (layer == 2) {
        #pragma unroll
        for (int q = 0; q < 4; ++q)
            pb[q] = bih2[q * 512 + j0 + lrow] + bhh2[q * 512 + j0 + lrow];
    }

    float creg[4] = {0.f, 0.f, 0.f, 0.f};
    const int brow16 = (w * 16 + lrow) << 4;

    for (int t = 0; t < 24; ++t) {
        // G0 prefetch (static, overlaps polls)
        float g0p[16];
        if (layer == 0) {
            const float* gp = G0 + (size_t)t * 64 * 2048;
            #pragma unroll
            for (int r = 0; r < 4; ++r) {
                int b = w * 16 + ((lane >> 4) << 2) + r;
                #pragma unroll
                for (int q = 0; q < 4; ++q)
                    g0p[r * 4 + q] = gp[(size_t)b * 2048 + q * 512 + j0 + lrow];
            }
        }

        const unsigned short* A0 = (layer == 0)
            ? hl + (size_t)t * HSLOT
            : hlow + (size_t)(t + 1) * HSLOT;
        const unsigned short* A1 = (layer == 0)
            ? A0
            : hl + (size_t)t * HSLOT;

        f32x4 acc[4] = {};
        bf16x8 bufA[8], bufB[8], bufC[8], bufD[8];

        if (layer == 0) {
            if (t > 0) {
                if (w == 0) {
                    POLL32(flags + (t - 1) * 32);
                    if (lane == 0)
                        __hip_atomic_store(&syncA[t], 1u, __ATOMIC_RELAXED,
                                           __HIP_MEMORY_SCOPE_WORKGROUP);
                } else {
                    LDS_SPIN(&syncA[t]);
                }
            }
            ISSUE_CHUNK(bufA, 0); ISSUE_CHUNK(bufB, 256);
            VM_WAIT(8); MFMA_CHUNK(bufA, 0);
            VM_WAIT(0); MFMA_CHUNK(bufB, 256);
        } else {
            // SPLIT CELL: own-layer half (h[l][t-1], 2 hops of slack) —
            // loads AND MFMAs execute before the lower-layer poll.
            if (t > 0) {
                if (w == 0) {
                    POLL32(flags + (layer * 24 + t - 1) * 32);
                    if (lane == 0)
                        __hip_atomic_store(&syncA[t], 1u, __ATOMIC_RELAXED,
                                           __HIP_MEMORY_SCOPE_WORKGROUP);
                } else {
                    LDS_SPIN(&syncA[t]);
                }
            }
            ISSUE_CHUNK(bufC, 512); ISSUE_CHUNK(bufD, 768);
            VM_WAIT(8); MFMA_CHUNK(bufC, 512);
            VM_WAIT(0); MFMA_CHUNK(bufD, 768);
            // critical inter-layer hop starts here
            if (w == 0) {
                POLL32(flags + ((layer - 1) * 24 + t) * 32);
                if (lane == 0)
                    __hip_atomic_store(&syncB[t], 1u, __ATOMIC_RELAXED,
                                       __HIP_MEMORY_SCOPE_WORKGROUP);
            } else {
                LDS_SPIN(&syncB[t]);
            }
            ISSUE_CHUNK(bufA, 0); ISSUE_CHUNK(bufB, 256);
            VM_WAIT(8); MFMA_CHUNK(bufA, 0);
            VM_WAIT(0); MFMA_CHUNK(bufB, 256);
        }

        // epilogue; h stores: full-line slab writes, sc1 write-through
        unsigned short* hslot = hl + (size_t)(t + 1) * HSLOT + (lbid << 10);
        #pragma unroll
        for (int r = 0; r < 4; ++r) {
            int b = w * 16 + ((lane >> 4) << 2) + r;
            float g[4];
            #pragma unroll
            for (int q = 0; q < 4; ++q) {
                float p = (layer == 0) ? g0p[r * 4 + q] : pb[q];
                g[q] = acc[q][r] + p;
            }
            float ig = fsig(g[0]);
            float fg = fsig(g[1]);
            float gg = ftanh(g[2]);
            float og = fsig(g[3]);
            float cn = fg * creg[r] + ig * gg;
            creg[r] = cn;
            float h = og * ftanh(cn);
            unsigned int hb = (unsigned int)f2b(h);
            unsigned short* hp = hslot + (b << 4) + lrow;
            asm volatile("global_store_short %0, %1, off sc1"
                         :: "v"(hp), "v"(hb) : "memory");
        }
        asm volatile("s_waitcnt vmcnt(0)" ::: "memory");
        if (lane == 0) {
            unsigned old = __hip_atomic_fetch_add(&lcnt[t], 1u, __ATOMIC_RELAXED,
                                                  __HIP_MEMORY_SCOPE_WORKGROUP);
            if (old == 3u)
                __hip_atomic_store(&flags[(layer * 24 + t) * 32 + lbid], 1u,
                                   __ATOMIC_RELAXED, __HIP_MEMORY_SCOPE_AGENT);
        }
    }
}

// ---- fc (512 threads): per-wave 32x64 sub-tile, cached A loads ----
#define FC_ISSUE_G(buf, mtv, ks0)                                             \
    {                                                                         \
        _Pragma("unroll")                                                     \
        for (int u_ = 0; u_ < 4; ++u_) {                                      \
            _Pragma("unroll")                                                 \
            for (int i_ = 0; i_ < 2; ++i_) {                                  \
                int b_ = brow + i_ * 16 + lrow;                               \
                int k_ = (ks0) + u_ * 32 + lk;                                \
                const unsigned short* ap_ = h2                                \
                    + (size_t)(2 * (mtv) + thalf + 1) * HSLOT                 \
                    + ((k_ >> 4) << 10) + (b_ << 4) + (k_ & 15);              \
                asm volatile("global_load_dwordx4 %0, %1, off"                \
                             : "=v"(buf[u_ * 2 + i_]) : "v"(ap_) : "memory"); \
            }                                                                 \
        }                                                                     \
    }
#define FC_MFMA_G(buf, ks0)                                                   \
    {                                                                         \
        _Pragma("unroll")                                                     \
        for (int u_ = 0; u_ < 4; ++u_) {                                      \
            int ks_ = (ks0) + u_ * 32 + lk;                                   \
            _Pragma("unroll")                                                 \
            for (int jj_ = 0; jj_ < 4; ++jj_) {                               \
                int row_ = wn * 64 + jj_ * 16 + lrow;                         \
                int gx_ = ((ks_ >> 3) ^ (row_ & 7)) << 3;                     \
                bf16x8 bq_ = *(const bf16x8*)&lB[row_ * 512 + gx_];           \
                _Pragma("unroll")                                             \
                for (int i_ = 0; i_ < 2; ++i_)                                \
                    acc[i_][jj_] = __builtin_amdgcn_mfma_f32_16x16x32_bf16(   \
                        buf[u_ * 2 + i_], bq_, acc[i_][jj_], 0, 0, 0);        \
            }                                                                 \
        }                                                                     \
    }
#define FC_STORES                                                             \
    {                                                                         \
        int t_ = 2 * mt + thalf;                                              \
        _Pragma("unroll")                                                     \
        for (int i_ = 0; i_ < 2; ++i_) {                                      \
            _Pragma("unroll")                                                 \
            for (int r_ = 0; r_ < 4; ++r_) {                                  \
                int b_ = brow + i_ * 16 + ((lane >> 4) << 2) + r_;            \
                float* orow_ = &out[(size_t)(b_ * 24 + t_) * 32000];          \
                _Pragma("unroll")                                             \
                for (int jj_ = 0; jj_ < 4; ++jj_) {                           \
                    int n_ = n0 + wn * 64 + jj_ * 16 + lrow;                  \
                    __builtin_nontemporal_store(                              \
                        acc[i_][jj_][r_] + fcb[n_], &orow_[n_]);              \
                }                                                             \
            }                                                                 \
        }                                                                     \
    }

// ---------------- fc GEMM (250 blocks x 512 threads) ----------------
__global__ __launch_bounds__(512, 1) void fc_gemm(
    const unsigned short* __restrict__ hst,
    const float* __restrict__ fcW,
    const float* __restrict__ fcb,
    float* __restrict__ out)
{
    extern __shared__ char smem[];
    unsigned short* lB = (unsigned short*)smem;    // [128][512] bf16 swizzled
    const int tid = threadIdx.x;
    const int lane = tid & 63, w = tid >> 6;       // w in 0..7
    const int lrow = lane & 15, lk = (lane >> 4) * 8;
    const int wm = w >> 1, wn = w & 1;
    const int thalf = wm >> 1;
    const int brow = (wm & 1) * 32;
    const unsigned short* h2 = hst + (size_t)2 * 25 * HSLOT;
    const int n0 = blockIdx.x * 128;

    // stage fcW panel once: f32 -> bf16, XOR swizzle
    for (int idx = tid; idx < 128 * 64; idx += 512) {
        int row = idx >> 6, g = idx & 63;
        const float* bp = &fcW[(size_t)(n0 + row) * 512 + g * 8];
        f32x4 v0 = *(const f32x4*)bp;
        f32x4 v1 = *(const f32x4*)(bp + 4);
        unsigned short o[8];
        #pragma unroll
        for (int x = 0; x < 4; ++x) { o[x] = f2b(v0[x]); o[4 + x] = f2b(v1[x]); }
        *(bf16x8*)&lB[row * 512 + ((g ^ (row & 7)) << 3)] = *(bf16x8*)o;
    }
    __syncthreads();

    bf16x8 gA[8], gB[8];

    // ---- tile 0 (peeled: no stores in flight)
    {
        const int mt = 0;
        f32x4 acc[2][4] = {};
        FC_ISSUE_G(gA, 0, 0); FC_ISSUE_G(gB, 0, 128);
        VM_WAIT(8); FC_MFMA_G(gA, 0);
        FC_ISSUE_G(gA, 0, 256);
        VM_WAIT(8); FC_MFMA_G(gB, 128);
        FC_ISSUE_G(gB, 0, 384);
        VM_WAIT(8); FC_MFMA_G(gA, 256);
        VM_WAIT(0); FC_MFMA_G(gB, 384);
        FC_ISSUE_G(gA, 1, 0); FC_ISSUE_G(gB, 1, 128);   // prefetch next
        FC_STORES;                                      // 32 stores
    }

    for (int mt = 1; mt < 12; ++mt) {
        f32x4 acc[2][4] = {};
        // entry: 16 loads (oldest) + 32 stores = 48 outstanding.
        // vmcnt(32) retires exactly the 16 loads.
        VM_WAIT(32);
        FC_MFMA_G(gA, 0);
        FC_ISSUE_G(gA, mt, 256);
        FC_MFMA_G(gB, 128);
        FC_ISSUE_G(gB, mt, 384);
        VM_WAIT(8);
        FC_MFMA_G(gA, 256);
        VM_WAIT(0);
        FC_MFMA_G(gB, 384);
        if (mt < 11) { FC_ISSUE_G(gA, mt + 1, 0); FC_ISSUE_G(gB, mt + 1, 128); }
        FC_STORES;
    }
}

// ---------------- launch ----------------
extern "C" void kernel_launch(void* const* d_in, const int* in_sizes, int n_in,
                              void* d_out, int out_size, void* d_ws, size_t ws_size,
                              hipStream_t stream) {
    const float* qf  = (const float*)d_in[0];
    const float* imf = (const float*)d_in[1];
    const int*   seq = (const int*)d_in[2];
    const float* emb = (const float*)d_in[3];
    // d_in[4..6] dead code
    const float* fcW = (const float*)d_in[7];
    const float* fcb = (const float*)d_in[8];
    const float* Wih[3] = {(const float*)d_in[9],  (const float*)d_in[13], (const float*)d_in[17]};
    const float* Whh[3] = {(const float*)d_in[10], (const float*)d_in[14], (const float*)d_in[18]};
    const float* bih[3] = {(const float*)d_in[11], (const float*)d_in[15], (const float*)d_in[19]};
    const float* bhh[3] = {(const float*)d_in[12], (const float*)d_in[16], (const float*)d_in[20]};

    char* ws = (char*)d_ws;
    unsigned short* X     = (unsigned short*)(ws + 0);          // 3,932,160
    float*          G0    = (float*)(ws + 3932160);             // 12,582,912
    unsigned short* hst   = (unsigned short*)(ws + 16515072);   // 4,915,200
    unsigned int*   flags = (unsigned int*)(ws + 21430272);     // 9,216
    unsigned short* Wpk   = (unsigned short*)(ws + 21467136);   // 10,485,760

    // 0) build_x + zero(flags, h slot0)
    prep<<<1544, 256, 0, stream>>>(qf, imf, seq, emb, X, flags, hst);

    // 1) G0 GEMM (blocks 0..191) + pack_w (192..6335), one dispatch
    g0pack<<<6336, 256, 0, stream>>>(
        X, Wih[0], bih[0], bhh[0], G0,
        Whh[0], Wih[1], Whh[1], Wih[2], Whh[2], Wpk);

    // 2) wavefront: 96 blocks, 128 KiB dynamic LDS
    lstm_wave<<<NLSTM, 256, 131072, stream>>>(
        Wpk, G0, bih[1], bhh[1], bih[2], bhh[2], hst, flags);

    // 3) fc: 250 blocks x 512 threads, 128 KiB dynamic LDS
    fc_gemm<<<NTILE_N, 512, 131072, stream>>>(
        hst, fcW, fcb, (float*)d_out);
}